// Round 1
// baseline (1106.177 us; speedup 1.0000x reference)
//
#include <hip/hip_runtime.h>
#include <math.h>

#define TT 2048
#define DD 256
#define NBATCH 8
#define EPSF 1e-8f

// ---------------------------------------------------------------------------
// Tiled NT GEMM: C[m,n] = act(scale * sum_k (A[m,k] (+A2[m,k])) * B[n,k])
// 64x64 tile, K-tile 32, 256 threads, 4x4 accum/thread.
// LDS tiles stored transposed [k][m] (pad 68 keeps 16B alignment) so the
// inner loop is 2x ds_read_b128 + 16 v_fma_f32 per k (VALU-bound).
// grid.z batches via strides (0 strides => shared).
// ---------------------------------------------------------------------------
__global__ __launch_bounds__(256)
void gemm_nt(const float* __restrict__ A, const float* __restrict__ A2,
             const float* __restrict__ B, float* __restrict__ C,
             int M, int N, int K,
             long sAz, long sBz, long sCz, float scale, int do_relu)
{
    __shared__ float As[32][68];
    __shared__ float Bs[32][68];
    const int z = blockIdx.z;
    const float* Ab = A + (long)z * sAz;
    const float* Bb = B + (long)z * sBz;
    float* Cb = C + (long)z * sCz;
    const int m0 = blockIdx.y * 64;
    const int n0 = blockIdx.x * 64;
    const int tid = threadIdx.x;
    const int tx = tid & 15, ty = tid >> 4;
    float acc[4][4] = {{0.f, 0.f, 0.f, 0.f}};

    for (int k0 = 0; k0 < K; k0 += 32) {
        for (int q = tid; q < 512; q += 256) {
            int m = q >> 3, k4 = (q & 7) << 2;
            float4 v = *(const float4*)(Ab + (long)(m0 + m) * K + k0 + k4);
            if (A2) {
                float4 w = *(const float4*)(A2 + (long)z * sAz + (long)(m0 + m) * K + k0 + k4);
                v.x += w.x; v.y += w.y; v.z += w.z; v.w += w.w;
            }
            As[k4 + 0][m] = v.x; As[k4 + 1][m] = v.y;
            As[k4 + 2][m] = v.z; As[k4 + 3][m] = v.w;
        }
        for (int q = tid; q < 512; q += 256) {
            int n = q >> 3, k4 = (q & 7) << 2;
            float4 v = *(const float4*)(Bb + (long)(n0 + n) * K + k0 + k4);
            Bs[k4 + 0][n] = v.x; Bs[k4 + 1][n] = v.y;
            Bs[k4 + 2][n] = v.z; Bs[k4 + 3][n] = v.w;
        }
        __syncthreads();
        #pragma unroll
        for (int kk = 0; kk < 32; ++kk) {
            const float4 a4 = *(const float4*)&As[kk][ty << 2];
            const float4 b4 = *(const float4*)&Bs[kk][tx << 2];
            const float a[4] = {a4.x, a4.y, a4.z, a4.w};
            const float b[4] = {b4.x, b4.y, b4.z, b4.w};
            #pragma unroll
            for (int i = 0; i < 4; ++i)
                #pragma unroll
                for (int j = 0; j < 4; ++j)
                    acc[i][j] = fmaf(a[i], b[j], acc[i][j]);
        }
        __syncthreads();
    }
    #pragma unroll
    for (int i = 0; i < 4; ++i) {
        float v0 = acc[i][0] * scale, v1 = acc[i][1] * scale;
        float v2 = acc[i][2] * scale, v3 = acc[i][3] * scale;
        if (do_relu) {
            v0 = fmaxf(v0, 0.f); v1 = fmaxf(v1, 0.f);
            v2 = fmaxf(v2, 0.f); v3 = fmaxf(v3, 0.f);
        }
        float4 o; o.x = v0; o.y = v1; o.z = v2; o.w = v3;
        *(float4*)(Cb + (long)(m0 + (ty << 2) + i) * N + n0 + (tx << 2)) = o;
    }
}

// ---------------------------------------------------------------------------
// Row sums (rs) and column sums (cs) of beta, per batch, via atomics.
// ---------------------------------------------------------------------------
__global__ __launch_bounds__(256)
void sums_kernel(const float* __restrict__ beta, float* __restrict__ rs,
                 float* __restrict__ cs, int batch0)
{
    __shared__ float sm[64][65];
    const int z = blockIdx.z;
    const float* Bt = beta + (long)z * TT * TT;
    const int r0 = blockIdx.y * 64, c0 = blockIdx.x * 64;
    const int tid = threadIdx.x;
    const int rbase = tid >> 4;
    const int c4 = (tid & 15) << 2;
    #pragma unroll
    for (int rr = 0; rr < 4; ++rr) {
        int r = rbase + rr * 16;
        float4 v = *(const float4*)(Bt + (long)(r0 + r) * TT + c0 + c4);
        sm[r][c4 + 0] = v.x; sm[r][c4 + 1] = v.y;
        sm[r][c4 + 2] = v.z; sm[r][c4 + 3] = v.w;
    }
    __syncthreads();
    const int b = batch0 + z;
    if (tid < 64) {
        float s = 0.f;
        #pragma unroll 8
        for (int k = 0; k < 64; ++k) s += sm[tid][k];
        atomicAdd(&rs[(long)b * TT + r0 + tid], s);
    } else if (tid < 128) {
        int c = tid - 64;
        float s = 0.f;
        #pragma unroll 8
        for (int k = 0; k < 64; ++k) s += sm[k][c];
        atomicAdd(&cs[(long)b * TT + c0 + c], s);
    }
}

// ---------------------------------------------------------------------------
// Thresholded row/col sums: rst[t] = sum_s beta[t,s]*(beta[t,s] > thr*(rs[t]+EPS))
//                           cst[t] = sum_s beta[s,t]*(beta[s,t] > thr*(cs[t]+EPS))
// ---------------------------------------------------------------------------
__global__ __launch_bounds__(256)
void sums_thr_kernel(const float* __restrict__ beta, const float* __restrict__ rs,
                     const float* __restrict__ cs, float* __restrict__ rst,
                     float* __restrict__ cst, const float* __restrict__ thrp, int batch0)
{
    __shared__ float sm[64][65];
    const int z = blockIdx.z;
    const float* Bt = beta + (long)z * TT * TT;
    const int r0 = blockIdx.y * 64, c0 = blockIdx.x * 64;
    const int tid = threadIdx.x;
    const int rbase = tid >> 4;
    const int c4 = (tid & 15) << 2;
    #pragma unroll
    for (int rr = 0; rr < 4; ++rr) {
        int r = rbase + rr * 16;
        float4 v = *(const float4*)(Bt + (long)(r0 + r) * TT + c0 + c4);
        sm[r][c4 + 0] = v.x; sm[r][c4 + 1] = v.y;
        sm[r][c4 + 2] = v.z; sm[r][c4 + 3] = v.w;
    }
    __syncthreads();
    const float thr = thrp[0] * 10.0f / (float)TT;
    const int b = batch0 + z;
    if (tid < 64) {
        const float cthr = thr * (rs[(long)b * TT + r0 + tid] + EPSF);
        float s = 0.f;
        #pragma unroll 8
        for (int k = 0; k < 64; ++k) {
            float v = sm[tid][k];
            if (v > cthr) s += v;
        }
        atomicAdd(&rst[(long)b * TT + r0 + tid], s);
    } else if (tid < 128) {
        int c = tid - 64;
        const float cthr = thr * (cs[(long)b * TT + c0 + c] + EPSF);
        float s = 0.f;
        #pragma unroll 8
        for (int k = 0; k < 64; ++k) {
            float v = sm[k][c];
            if (v > cthr) s += v;
        }
        atomicAdd(&cst[(long)b * TT + c0 + c], s);
    }
}

// ---------------------------------------------------------------------------
// PV: Out[m,n] = inv[m] * sum_k pass(Beta(m,k)) * V[k,n]
//   transA=0: Beta(m,k) = beta[m,k]   (v attends a; norm arrays = rs/rst)
//   transA=1: Beta(m,k) = beta[k,m]   (a attends v; norm arrays = cs/cst)
// pass(x) = x if x > thr*(sum_all[m]+EPS) else 0
// inv[m]  = 1/(sum_thr[m] + EPS*(sum_all[m]+EPS))
// ---------------------------------------------------------------------------
__global__ __launch_bounds__(256)
void pv_kernel(const float* __restrict__ beta, const float* __restrict__ V,
               float* __restrict__ Out, const float* __restrict__ sum_all,
               const float* __restrict__ sum_thr, const float* __restrict__ thrp,
               int transA, int batch0)
{
    __shared__ float As[32][68];
    __shared__ float Bs[32][68];
    __shared__ float cArr[64];
    __shared__ float invArr[64];
    const int z = blockIdx.z;
    const float* Bt = beta + (long)z * TT * TT;
    const float* Vb = V + (long)z * TT * DD;
    float* Ob = Out + (long)z * TT * DD;
    const int m0 = blockIdx.y * 64, n0 = blockIdx.x * 64;
    const int tid = threadIdx.x;
    const int b = batch0 + z;
    const float thr = thrp[0] * 10.0f / (float)TT;
    if (tid < 64) {
        float sa = sum_all[(long)b * TT + m0 + tid];
        float st = sum_thr[(long)b * TT + m0 + tid];
        cArr[tid] = thr * (sa + EPSF);
        invArr[tid] = 1.0f / (st + EPSF * (sa + EPSF));
    }
    __syncthreads();
    const int tx = tid & 15, ty = tid >> 4;
    float acc[4][4] = {{0.f, 0.f, 0.f, 0.f}};

    for (int k0 = 0; k0 < TT; k0 += 32) {
        if (!transA) {
            for (int q = tid; q < 512; q += 256) {
                int m = q >> 3, k4 = (q & 7) << 2;
                float4 v = *(const float4*)(Bt + (long)(m0 + m) * TT + k0 + k4);
                const float c = cArr[m];
                As[k4 + 0][m] = v.x > c ? v.x : 0.f;
                As[k4 + 1][m] = v.y > c ? v.y : 0.f;
                As[k4 + 2][m] = v.z > c ? v.z : 0.f;
                As[k4 + 3][m] = v.w > c ? v.w : 0.f;
            }
        } else {
            for (int q = tid; q < 512; q += 256) {
                int k = q >> 4, m4 = (q & 15) << 2;
                float4 v = *(const float4*)(Bt + (long)(k0 + k) * TT + m0 + m4);
                float4 o;
                o.x = v.x > cArr[m4 + 0] ? v.x : 0.f;
                o.y = v.y > cArr[m4 + 1] ? v.y : 0.f;
                o.z = v.z > cArr[m4 + 2] ? v.z : 0.f;
                o.w = v.w > cArr[m4 + 3] ? v.w : 0.f;
                *(float4*)&As[k][m4] = o;
            }
        }
        for (int q = tid; q < 512; q += 256) {
            int k = q >> 4, n4 = (q & 15) << 2;
            float4 v = *(const float4*)(Vb + (long)(k0 + k) * DD + n0 + n4);
            *(float4*)&Bs[k][n4] = v;
        }
        __syncthreads();
        #pragma unroll
        for (int kk = 0; kk < 32; ++kk) {
            const float4 a4 = *(const float4*)&As[kk][ty << 2];
            const float4 b4 = *(const float4*)&Bs[kk][tx << 2];
            const float a[4] = {a4.x, a4.y, a4.z, a4.w};
            const float bb[4] = {b4.x, b4.y, b4.z, b4.w};
            #pragma unroll
            for (int i = 0; i < 4; ++i)
                #pragma unroll
                for (int j = 0; j < 4; ++j)
                    acc[i][j] = fmaf(a[i], bb[j], acc[i][j]);
        }
        __syncthreads();
    }
    #pragma unroll
    for (int i = 0; i < 4; ++i) {
        const float inv = invArr[(ty << 2) + i];
        float4 o;
        o.x = acc[i][0] * inv; o.y = acc[i][1] * inv;
        o.z = acc[i][2] * inv; o.w = acc[i][3] * inv;
        *(float4*)(Ob + (long)(m0 + (ty << 2) + i) * DD + n0 + (tx << 2)) = o;
    }
}

// ---------------------------------------------------------------------------
// pred[t] = (beta[0][t][t] > thr*(cs[0][t]+EPS)) ? 1 : 0
// ---------------------------------------------------------------------------
__global__ __launch_bounds__(256)
void pred_kernel(const float* __restrict__ beta, const float* __restrict__ cs,
                 const float* __restrict__ thrp, float* __restrict__ pred)
{
    const int t = blockIdx.x * 256 + threadIdx.x;
    const float thr = thrp[0] * 10.0f / (float)TT;
    const float d = beta[(long)t * TT + t];
    pred[t] = (d > thr * (cs[t] + EPSF)) ? 1.0f : 0.0f;
}

// ---------------------------------------------------------------------------
// LayerNorm both branches + fuse. 4 rows/block, 1 wave per row.
// ---------------------------------------------------------------------------
__global__ __launch_bounds__(256)
void ln_fuse_kernel(const float* __restrict__ yv, const float* __restrict__ ya,
                    const float* __restrict__ g, const float* __restrict__ b,
                    float* __restrict__ fuse, float* __restrict__ vpsp,
                    float* __restrict__ apsp)
{
    const long row = (long)blockIdx.x * 4 + (threadIdx.x >> 6);
    const int lane = threadIdx.x & 63;
    const float4 xv = *(const float4*)(yv + row * DD + lane * 4);
    const float4 xa = *(const float4*)(ya + row * DD + lane * 4);
    float sv = xv.x + xv.y + xv.z + xv.w;
    float sa = xa.x + xa.y + xa.z + xa.w;
    #pragma unroll
    for (int off = 32; off > 0; off >>= 1) {
        sv += __shfl_xor(sv, off);
        sa += __shfl_xor(sa, off);
    }
    const float mv = sv * (1.f / 256.f);
    const float ma = sa * (1.f / 256.f);
    const float dv0 = xv.x - mv, dv1 = xv.y - mv, dv2 = xv.z - mv, dv3 = xv.w - mv;
    const float da0 = xa.x - ma, da1 = xa.y - ma, da2 = xa.z - ma, da3 = xa.w - ma;
    float qv = dv0 * dv0 + dv1 * dv1 + dv2 * dv2 + dv3 * dv3;
    float qa = da0 * da0 + da1 * da1 + da2 * da2 + da3 * da3;
    #pragma unroll
    for (int off = 32; off > 0; off >>= 1) {
        qv += __shfl_xor(qv, off);
        qa += __shfl_xor(qa, off);
    }
    const float rv = rsqrtf(qv * (1.f / 256.f) + 1e-6f);
    const float ra = rsqrtf(qa * (1.f / 256.f) + 1e-6f);
    const float4 gg = *(const float4*)(g + lane * 4);
    const float4 bb = *(const float4*)(b + lane * 4);
    float4 ov, oa, of;
    ov.x = dv0 * rv * gg.x + bb.x; ov.y = dv1 * rv * gg.y + bb.y;
    ov.z = dv2 * rv * gg.z + bb.z; ov.w = dv3 * rv * gg.w + bb.w;
    oa.x = da0 * ra * gg.x + bb.x; oa.y = da1 * ra * gg.y + bb.y;
    oa.z = da2 * ra * gg.z + bb.z; oa.w = da3 * ra * gg.w + bb.w;
    of.x = 0.5f * (ov.x + oa.x); of.y = 0.5f * (ov.y + oa.y);
    of.z = 0.5f * (ov.z + oa.z); of.w = 0.5f * (ov.w + oa.w);
    *(float4*)(vpsp + row * DD + lane * 4) = ov;
    *(float4*)(apsp + row * DD + lane * 4) = oa;
    *(float4*)(fuse + row * DD + lane * 4) = of;
}

extern "C" void kernel_launch(void* const* d_in, const int* in_sizes, int n_in,
                              void* d_out, int out_size, void* d_ws, size_t ws_size,
                              hipStream_t stream)
{
    const float* a_fea = (const float*)d_in[0];
    const float* v_fea = (const float*)d_in[1];
    const float* thrp  = (const float*)d_in[2];
    const float* Wv1   = (const float*)d_in[3];
    const float* Wv2   = (const float*)d_in[4];
    const float* Wvfc  = (const float*)d_in[5];
    const float* Wa1   = (const float*)d_in[6];
    const float* Wa2   = (const float*)d_in[7];
    const float* Wafc  = (const float*)d_in[8];
    const float* lng   = (const float*)d_in[9];
    const float* lnb   = (const float*)d_in[10];

    const long MT = (long)NBATCH * TT; // 16384 rows total
    float* out_fuse = (float*)d_out;
    float* out_vpsp = out_fuse + MT * DD;
    float* out_apsp = out_vpsp + MT * DD;
    float* out_pred = out_apsp + MT * DD;

    // workspace layout (all fp32):
    //   v1, v2, a1, a2, posv, posa : 6 x 16.78 MB
    //   rs, cs, rst, cst           : 4 x 64 KB
    //   beta                       : G x 16.78 MB (batch-grouped)
    // y_v aliases v2, y_a aliases a1 (dead after the last score GEMM).
    char* ws = (char*)d_ws;
    const size_t featB = (size_t)MT * DD * sizeof(float);
    const size_t sumB  = (size_t)MT * sizeof(float);
    float* v1   = (float*)(ws + 0 * featB);
    float* v2   = (float*)(ws + 1 * featB);
    float* a1   = (float*)(ws + 2 * featB);
    float* a2   = (float*)(ws + 3 * featB);
    float* posv = (float*)(ws + 4 * featB);
    float* posa = (float*)(ws + 5 * featB);
    char* p = ws + 6 * featB;
    float* rs   = (float*)(p + 0 * sumB);
    float* cs   = (float*)(p + 1 * sumB);
    float* rst  = (float*)(p + 2 * sumB);
    float* cst  = (float*)(p + 3 * sumB);
    float* beta = (float*)(p + 4 * sumB);

    const size_t used = 6 * featB + 4 * sumB;
    const size_t betaOne = (size_t)TT * TT * sizeof(float);
    int G = 1;
    if (ws_size > used + betaOne) {
        size_t gmax = (ws_size - used) / betaOne;
        G = (int)(gmax > NBATCH ? NBATCH : gmax);
        if (G < 1) G = 1;
    }

    hipMemsetAsync(rs, 0, 4 * sumB, stream);

    const dim3 blk(256, 1, 1);

    // branch projections (fp32 NT GEMMs; v2/a1 feed the threshold-critical scores)
    gemm_nt<<<dim3(DD / 64, MT / 64, 1), blk, 0, stream>>>(v_fea, nullptr, Wv1, v1,
        (int)MT, DD, DD, 0, 0, 0, 1.f, 1);
    gemm_nt<<<dim3(DD / 64, MT / 64, 1), blk, 0, stream>>>(v_fea, nullptr, Wv2, v2,
        (int)MT, DD, DD, 0, 0, 0, 1.f, 1);
    gemm_nt<<<dim3(DD / 64, MT / 64, 1), blk, 0, stream>>>(a_fea, nullptr, Wa1, a1,
        (int)MT, DD, DD, 0, 0, 0, 1.f, 1);
    gemm_nt<<<dim3(DD / 64, MT / 64, 1), blk, 0, stream>>>(a_fea, nullptr, Wa2, a2,
        (int)MT, DD, DD, 0, 0, 0, 1.f, 1);

    for (int g0 = 0; g0 < NBATCH; g0 += G) {
        const int g = (NBATCH - g0 < G) ? (NBATCH - g0) : G;
        // beta_va[b,t,s] = relu(v2[b,t]·a1[b,s] / 16)
        gemm_nt<<<dim3(TT / 64, TT / 64, g), blk, 0, stream>>>(
            v2 + (long)g0 * TT * DD, nullptr, a1 + (long)g0 * TT * DD, beta,
            TT, TT, DD, (long)TT * DD, (long)TT * DD, (long)TT * TT, 1.f / 16.f, 1);
        sums_kernel<<<dim3(TT / 64, TT / 64, g), blk, 0, stream>>>(beta, rs, cs, g0);
        if (g0 == 0)
            pred_kernel<<<dim3(TT / 256, 1, 1), blk, 0, stream>>>(beta, cs, thrp, out_pred);
        sums_thr_kernel<<<dim3(TT / 64, TT / 64, g), blk, 0, stream>>>(
            beta, rs, cs, rst, cst, thrp, g0);
        // a_pos = g_va @ a2  (added to v_fea later)
        pv_kernel<<<dim3(DD / 64, TT / 64, g), blk, 0, stream>>>(
            beta, a2 + (long)g0 * TT * DD, posv + (long)g0 * TT * DD,
            rs, rst, thrp, 0, g0);
        // v_pos = g_av @ v1  (added to a_fea later)
        pv_kernel<<<dim3(DD / 64, TT / 64, g), blk, 0, stream>>>(
            beta, v1 + (long)g0 * TT * DD, posa + (long)g0 * TT * DD,
            cs, cst, thrp, 1, g0);
    }

    // final FC: y = relu((feat + pos) @ Wfc^T); y_v aliases v2, y_a aliases a1
    gemm_nt<<<dim3(DD / 64, MT / 64, 1), blk, 0, stream>>>(v_fea, posv, Wvfc, v2,
        (int)MT, DD, DD, 0, 0, 0, 1.f, 1);
    gemm_nt<<<dim3(DD / 64, MT / 64, 1), blk, 0, stream>>>(a_fea, posa, Wafc, a1,
        (int)MT, DD, DD, 0, 0, 0, 1.f, 1);
    ln_fuse_kernel<<<dim3(MT / 4, 1, 1), blk, 0, stream>>>(
        v2, a1, lng, lnb, out_fuse, out_vpsp, out_apsp);
}

// Round 2
// 730.089 us; speedup vs baseline: 1.5151x; 1.5151x over previous
//
#include <hip/hip_runtime.h>
#include <math.h>

#define TT 2048
#define DD 256
#define NBATCH 8
#define EPSF 1e-8f

typedef unsigned short u16;
typedef __attribute__((ext_vector_type(8))) short short8;
typedef __attribute__((ext_vector_type(4))) float f32x4;

__device__ __forceinline__ u16 f2bf(float x) {
    unsigned int u = __builtin_bit_cast(unsigned int, x);
    u += 0x7fffu + ((u >> 16) & 1u);
    return (u16)(u >> 16);
}
__device__ __forceinline__ float bf2f(u16 h) {
    return __builtin_bit_cast(float, (unsigned int)h << 16);
}

// ---------------------------------------------------------------------------
// fp32 tiled NT GEMM (exact) — used for the 4 branch projections.
// epi=1: write relu(out) as split bf16 (h to Ch, l to Cl)  [v2, a1 -> scores]
// epi=2: write relu(out) as bf16 (h to Ch)                 [v1, a2 -> PV values]
// ---------------------------------------------------------------------------
__global__ __launch_bounds__(256)
void gemm_nt(const float* __restrict__ A, const float* __restrict__ B,
             float* __restrict__ C, u16* __restrict__ Ch, u16* __restrict__ Cl,
             int M, int N, int K, float scale, int epi)
{
    __shared__ float As[32][68];
    __shared__ float Bs[32][68];
    const int m0 = blockIdx.y * 64;
    const int n0 = blockIdx.x * 64;
    const int tid = threadIdx.x;
    const int tx = tid & 15, ty = tid >> 4;
    float acc[4][4] = {{0.f, 0.f, 0.f, 0.f}};

    for (int k0 = 0; k0 < K; k0 += 32) {
        for (int q = tid; q < 512; q += 256) {
            int m = q >> 3, k4 = (q & 7) << 2;
            float4 v = *(const float4*)(A + (long)(m0 + m) * K + k0 + k4);
            As[k4 + 0][m] = v.x; As[k4 + 1][m] = v.y;
            As[k4 + 2][m] = v.z; As[k4 + 3][m] = v.w;
        }
        for (int q = tid; q < 512; q += 256) {
            int n = q >> 3, k4 = (q & 7) << 2;
            float4 v = *(const float4*)(B + (long)(n0 + n) * K + k0 + k4);
            Bs[k4 + 0][n] = v.x; Bs[k4 + 1][n] = v.y;
            Bs[k4 + 2][n] = v.z; Bs[k4 + 3][n] = v.w;
        }
        __syncthreads();
        #pragma unroll
        for (int kk = 0; kk < 32; ++kk) {
            const float4 a4 = *(const float4*)&As[kk][ty << 2];
            const float4 b4 = *(const float4*)&Bs[kk][tx << 2];
            const float a[4] = {a4.x, a4.y, a4.z, a4.w};
            const float b[4] = {b4.x, b4.y, b4.z, b4.w};
            #pragma unroll
            for (int i = 0; i < 4; ++i)
                #pragma unroll
                for (int j = 0; j < 4; ++j)
                    acc[i][j] = fmaf(a[i], b[j], acc[i][j]);
        }
        __syncthreads();
    }
    #pragma unroll
    for (int i = 0; i < 4; ++i) {
        const int row = m0 + (ty << 2) + i;
        float v[4];
        #pragma unroll
        for (int j = 0; j < 4; ++j) v[j] = fmaxf(acc[i][j] * scale, 0.f);
        if (epi == 0) {
            float4 o; o.x = v[0]; o.y = v[1]; o.z = v[2]; o.w = v[3];
            *(float4*)(C + (long)row * N + n0 + (tx << 2)) = o;
        } else {
            ushort4 h4, l4;
            u16 h, l;
            h = f2bf(v[0]); l = f2bf(v[0] - bf2f(h)); h4.x = h; l4.x = l;
            h = f2bf(v[1]); l = f2bf(v[1] - bf2f(h)); h4.y = h; l4.y = l;
            h = f2bf(v[2]); l = f2bf(v[2] - bf2f(h)); h4.z = h; l4.z = l;
            h = f2bf(v[3]); l = f2bf(v[3] - bf2f(h)); h4.w = h; l4.w = l;
            *(ushort4*)(Ch + (long)row * N + n0 + (tx << 2)) = h4;
            if (epi == 1)
                *(ushort4*)(Cl + (long)row * N + n0 + (tx << 2)) = l4;
        }
    }
}

// ---------------------------------------------------------------------------
// Stage a [BR rows x 32 k] bf16 tile from global ([row][k] layout, k contig)
// into LDS in MFMA-fragment-swizzled order:
//   elem(row, k) -> (((row>>4)*4 + (k>>3))*16 + (row&15))*8 + (k&7)
// so a wave's fragment read for 16-row tile rt is a linear ds_read_b128 at
// (rt*64 + lane)*8 elements — conflict-free.
// ---------------------------------------------------------------------------
template<int BR>
__device__ __forceinline__ void stage_tile(const u16* __restrict__ g, u16* s,
                                           int row0, int k0, int ldk, int tid)
{
    #pragma unroll
    for (int i = 0; i < BR / 64; ++i) {
        const int c = tid + 256 * i;
        const int row = c >> 2, q = c & 3;
        const int dst = (((row >> 4) * 4 + q) * 16 + (row & 15)) * 8;
        *(int4*)(s + dst) = *(const int4*)(g + (long)(row0 + row) * ldk + k0 + q * 8);
    }
}

// ---------------------------------------------------------------------------
// bf16 MFMA NT GEMM. A [m][k], B [n][k] (both k-contiguous), 256 thr, 2x2 waves.
// NTERM=4: split inputs (Ah+Al)x(Bh+Bl) — near-fp32 accuracy (err ~1e-5 rel).
// EPI=0: Cf = relu(acc*scale)  (fp32)
// EPI=1: Cb = bf16(acc * inv[m] + resid[m][n]),
//        inv = 1/(sum_thr + EPS*(sum_all+EPS))   [PV + renorm + residual]
// ---------------------------------------------------------------------------
template<int NTERM, int BM, int BN, int EPI>
__global__ __launch_bounds__(256)
void mfma_nt(const u16* __restrict__ Ah, const u16* __restrict__ Al,
             const u16* __restrict__ Bh, const u16* __restrict__ Bl,
             float* __restrict__ Cf, u16* __restrict__ Cb,
             const float* __restrict__ resid,
             const float* __restrict__ sum_all, const float* __restrict__ sum_thr,
             int M, int N, int K, int lda, int ldb,
             long sAz, long sBz, long sCz, float scale)
{
    constexpr int WM = BM / 32;   // m-tiles per wave
    constexpr int WN = BN / 32;   // n-tiles per wave
    __shared__ __align__(16) u16 Ah_s[BM * 32];
    __shared__ __align__(16) u16 Bh_s[BN * 32];
    __shared__ __align__(16) u16 Al_s[NTERM == 4 ? BM * 32 : 8];
    __shared__ __align__(16) u16 Bl_s[NTERM == 4 ? BN * 32 : 8];
    const int z = blockIdx.z;
    const int m0 = blockIdx.y * BM, n0 = blockIdx.x * BN;
    const int tid = threadIdx.x;
    const int lane = tid & 63, w = tid >> 6;
    const int wy = w >> 1, wx = w & 1;
    f32x4 acc[WM][WN] = {};

    for (int k0 = 0; k0 < K; k0 += 32) {
        stage_tile<BM>(Ah + (long)z * sAz, Ah_s, m0, k0, lda, tid);
        stage_tile<BN>(Bh + (long)z * sBz, Bh_s, n0, k0, ldb, tid);
        if (NTERM == 4) {
            stage_tile<BM>(Al + (long)z * sAz, Al_s, m0, k0, lda, tid);
            stage_tile<BN>(Bl + (long)z * sBz, Bl_s, n0, k0, ldb, tid);
        }
        __syncthreads();
        short8 ah[WM], bh[WN], al[WM], bl[WN];
        #pragma unroll
        for (int i = 0; i < WM; ++i) {
            ah[i] = *(const short8*)(Ah_s + ((wy * WM + i) * 64 + lane) * 8);
            if (NTERM == 4)
                al[i] = *(const short8*)(Al_s + ((wy * WM + i) * 64 + lane) * 8);
        }
        #pragma unroll
        for (int j = 0; j < WN; ++j) {
            bh[j] = *(const short8*)(Bh_s + ((wx * WN + j) * 64 + lane) * 8);
            if (NTERM == 4)
                bl[j] = *(const short8*)(Bl_s + ((wx * WN + j) * 64 + lane) * 8);
        }
        #pragma unroll
        for (int i = 0; i < WM; ++i)
            #pragma unroll
            for (int j = 0; j < WN; ++j) {
                if (NTERM == 4) {
                    acc[i][j] = __builtin_amdgcn_mfma_f32_16x16x32_bf16(al[i], bl[j], acc[i][j], 0, 0, 0);
                    acc[i][j] = __builtin_amdgcn_mfma_f32_16x16x32_bf16(al[i], bh[j], acc[i][j], 0, 0, 0);
                    acc[i][j] = __builtin_amdgcn_mfma_f32_16x16x32_bf16(ah[i], bl[j], acc[i][j], 0, 0, 0);
                }
                acc[i][j] = __builtin_amdgcn_mfma_f32_16x16x32_bf16(ah[i], bh[j], acc[i][j], 0, 0, 0);
            }
        __syncthreads();
    }

    // epilogue: C/D layout col=lane&15, row=(lane>>4)*4+reg  [m89/m91 verified]
    const int quad = lane >> 4, col = lane & 15;
    #pragma unroll
    for (int i = 0; i < WM; ++i) {
        const int rbase = m0 + (wy * WM + i) * 16 + quad * 4;
        #pragma unroll
        for (int j = 0; j < WN; ++j) {
            const int c = n0 + (wx * WN + j) * 16 + col;
            #pragma unroll
            for (int r = 0; r < 4; ++r) {
                const int row = rbase + r;
                float v = acc[i][j][r];
                if (EPI == 0) {
                    v = fmaxf(v * scale, 0.f);
                    Cf[(long)z * sCz + (long)row * N + c] = v;
                } else {
                    const float sa = sum_all[(long)z * TT + row];
                    const float st = sum_thr[(long)z * TT + row];
                    const float inv = 1.0f / (st + EPSF * (sa + EPSF));
                    v = v * inv + resid[(long)z * sCz + (long)row * N + c];
                    Cb[(long)z * sCz + (long)row * N + c] = f2bf(v);
                }
            }
        }
    }
}

// ---------------------------------------------------------------------------
// Row sums (rs) and column sums (cs) of beta, per batch, via atomics.
// ---------------------------------------------------------------------------
__global__ __launch_bounds__(256)
void sums_kernel(const float* __restrict__ beta, float* __restrict__ rs,
                 float* __restrict__ cs, int batch0)
{
    __shared__ float sm[64][65];
    const int z = blockIdx.z;
    const float* Bt = beta + (long)z * TT * TT;
    const int r0 = blockIdx.y * 64, c0 = blockIdx.x * 64;
    const int tid = threadIdx.x;
    const int rbase = tid >> 4;
    const int c4 = (tid & 15) << 2;
    #pragma unroll
    for (int rr = 0; rr < 4; ++rr) {
        int r = rbase + rr * 16;
        float4 v = *(const float4*)(Bt + (long)(r0 + r) * TT + c0 + c4);
        sm[r][c4 + 0] = v.x; sm[r][c4 + 1] = v.y;
        sm[r][c4 + 2] = v.z; sm[r][c4 + 3] = v.w;
    }
    __syncthreads();
    const int b = batch0 + z;
    if (tid < 64) {
        float s = 0.f;
        #pragma unroll 8
        for (int k = 0; k < 64; ++k) s += sm[tid][k];
        atomicAdd(&rs[(long)b * TT + r0 + tid], s);
    } else if (tid < 128) {
        int c = tid - 64;
        float s = 0.f;
        #pragma unroll 8
        for (int k = 0; k < 64; ++k) s += sm[k][c];
        atomicAdd(&cs[(long)b * TT + c0 + c], s);
    }
}

// ---------------------------------------------------------------------------
// Thresholded row/col sums AND emission of the pass matrices as bf16:
//   Pva [t][s]  = beta[t][s] if beta > thr*(rs[t]+EPS) else 0     (k-contig NT A)
//   PavT[t][s]  = beta[s][t] if beta[s][t] > thr*(cs[t]+EPS) else 0 (transposed)
// ---------------------------------------------------------------------------
__global__ __launch_bounds__(256)
void sums_thr_ext(const float* __restrict__ beta, const float* __restrict__ rs,
                  const float* __restrict__ cs, float* __restrict__ rst,
                  float* __restrict__ cst, const float* __restrict__ thrp,
                  u16* __restrict__ Pva, u16* __restrict__ PavT, int batch0)
{
    __shared__ float sm[64][65];
    __shared__ float rthr[64], cthr[64];
    const int z = blockIdx.z;
    const float* Bt = beta + (long)z * TT * TT;
    const int r0 = blockIdx.y * 64, c0 = blockIdx.x * 64;
    const int tid = threadIdx.x;
    const int rbase = tid >> 4;
    const int c4 = (tid & 15) << 2;
    #pragma unroll
    for (int rr = 0; rr < 4; ++rr) {
        int r = rbase + rr * 16;
        float4 v = *(const float4*)(Bt + (long)(r0 + r) * TT + c0 + c4);
        sm[r][c4 + 0] = v.x; sm[r][c4 + 1] = v.y;
        sm[r][c4 + 2] = v.z; sm[r][c4 + 3] = v.w;
    }
    const float thr = thrp[0] * 10.0f / (float)TT;
    const int b = batch0 + z;
    if (tid < 64)
        rthr[tid] = thr * (rs[(long)b * TT + r0 + tid] + EPSF);
    else if (tid < 128)
        cthr[tid - 64] = thr * (cs[(long)b * TT + c0 + tid - 64] + EPSF);
    __syncthreads();
    if (tid < 64) {
        const float ct = rthr[tid];
        float s = 0.f;
        #pragma unroll 8
        for (int k = 0; k < 64; ++k) {
            float v = sm[tid][k];
            if (v > ct) s += v;
        }
        atomicAdd(&rst[(long)b * TT + r0 + tid], s);
    } else if (tid < 128) {
        int c = tid - 64;
        const float ct = cthr[c];
        float s = 0.f;
        #pragma unroll 8
        for (int k = 0; k < 64; ++k) {
            float v = sm[k][c];
            if (v > ct) s += v;
        }
        atomicAdd(&cst[(long)b * TT + c0 + c], s);
    }
    {   // Pva: row-thresholded, natural layout
        const int r = tid >> 2, c16 = (tid & 3) * 16;
        const float ct = rthr[r];
        unsigned pk[8];
        #pragma unroll
        for (int q = 0; q < 8; ++q) {
            float v0 = sm[r][c16 + 2 * q];
            float v1 = sm[r][c16 + 2 * q + 1];
            v0 = (v0 > ct) ? v0 : 0.f;
            v1 = (v1 > ct) ? v1 : 0.f;
            pk[q] = (unsigned)f2bf(v0) | ((unsigned)f2bf(v1) << 16);
        }
        u16* dst = Pva + (long)z * TT * TT + (long)(r0 + r) * TT + c0 + c16;
        *(int4*)dst = int4{(int)pk[0], (int)pk[1], (int)pk[2], (int)pk[3]};
        *(int4*)(dst + 8) = int4{(int)pk[4], (int)pk[5], (int)pk[6], (int)pk[7]};
    }
    {   // PavT: col-thresholded, transposed
        const int c = tid >> 2, r16 = (tid & 3) * 16;
        const float ct = cthr[c];
        unsigned pk[8];
        #pragma unroll
        for (int q = 0; q < 8; ++q) {
            float v0 = sm[r16 + 2 * q][c];
            float v1 = sm[r16 + 2 * q + 1][c];
            v0 = (v0 > ct) ? v0 : 0.f;
            v1 = (v1 > ct) ? v1 : 0.f;
            pk[q] = (unsigned)f2bf(v0) | ((unsigned)f2bf(v1) << 16);
        }
        u16* dst = PavT + (long)z * TT * TT + (long)(c0 + c) * TT + r0 + r16;
        *(int4*)dst = int4{(int)pk[0], (int)pk[1], (int)pk[2], (int)pk[3]};
        *(int4*)(dst + 8) = int4{(int)pk[4], (int)pk[5], (int)pk[6], (int)pk[7]};
    }
}

// ---------------------------------------------------------------------------
// Exact fp32 pred: recompute v2[0,t], a1[0,t] rows and their dot; compare.
// 8 t-rows per workgroup; thread j owns output dim j.
// ---------------------------------------------------------------------------
__global__ __launch_bounds__(256)
void pred_exact(const float* __restrict__ vf, const float* __restrict__ af,
                const float* __restrict__ Wv2, const float* __restrict__ Wa1,
                const float* __restrict__ cs, const float* __restrict__ thrp,
                float* __restrict__ pred)
{
    __shared__ float vs[8][260];
    __shared__ float as_[8][260];
    __shared__ float red[4][8];
    const int t0 = blockIdx.x * 8;
    const int tid = threadIdx.x;
    {
        const int i = tid >> 5, c = (tid & 31) * 8;
        *(float4*)&vs[i][c] = *(const float4*)(vf + (long)(t0 + i) * DD + c);
        *(float4*)&vs[i][c + 4] = *(const float4*)(vf + (long)(t0 + i) * DD + c + 4);
        *(float4*)&as_[i][c] = *(const float4*)(af + (long)(t0 + i) * DD + c);
        *(float4*)&as_[i][c + 4] = *(const float4*)(af + (long)(t0 + i) * DD + c + 4);
    }
    __syncthreads();
    const int j = tid;
    float av[8] = {0.f}, aa[8] = {0.f};
    for (int k = 0; k < DD; k += 4) {
        const float4 wv = *(const float4*)(Wv2 + (long)j * DD + k);
        const float4 wa = *(const float4*)(Wa1 + (long)j * DD + k);
        #pragma unroll
        for (int i = 0; i < 8; ++i) {
            const float4 x = *(const float4*)&vs[i][k];
            av[i] += wv.x * x.x + wv.y * x.y + wv.z * x.z + wv.w * x.w;
            const float4 y = *(const float4*)&as_[i][k];
            aa[i] += wa.x * y.x + wa.y * y.y + wa.z * y.z + wa.w * y.w;
        }
    }
    float p[8];
    #pragma unroll
    for (int i = 0; i < 8; ++i)
        p[i] = fmaxf(av[i], 0.f) * fmaxf(aa[i], 0.f);
    #pragma unroll
    for (int off = 32; off > 0; off >>= 1)
        #pragma unroll
        for (int i = 0; i < 8; ++i) p[i] += __shfl_xor(p[i], off);
    const int lane = tid & 63, wv_ = tid >> 6;
    if (lane == 0)
        #pragma unroll
        for (int i = 0; i < 8; ++i) red[wv_][i] = p[i];
    __syncthreads();
    if (tid < 8) {
        float d = red[0][tid] + red[1][tid] + red[2][tid] + red[3][tid];
        d = fmaxf(d * (1.f / 16.f), 0.f);
        const float thr = thrp[0] * 10.0f / (float)TT;
        pred[t0 + tid] = (d > thr * (cs[t0 + tid] + EPSF)) ? 1.0f : 0.0f;
    }
}

// ---------------------------------------------------------------------------
// Batch transpose bf16: [8][2048][256] -> [8][256][2048]; z<8: v1, z>=8: a2.
// ---------------------------------------------------------------------------
__global__ __launch_bounds__(256)
void transpose2(const u16* __restrict__ v1b, u16* __restrict__ v1T,
                const u16* __restrict__ a2b, u16* __restrict__ a2T)
{
    __shared__ u16 sm[64][72];
    const int zz = blockIdx.z;
    const u16* src = (zz < 8) ? v1b : a2b;
    u16* dst = (zz < 8) ? v1T : a2T;
    const int b = zz & 7;
    const int t0 = blockIdx.y * 64, d0 = blockIdx.x * 64;
    const int tid = threadIdx.x;
    {
        const int r = tid >> 2, c16 = (tid & 3) * 16;
        const u16* s = src + ((long)b * TT + t0 + r) * DD + d0 + c16;
        *(int4*)&sm[r][c16] = *(const int4*)s;
        *(int4*)&sm[r][c16 + 8] = *(const int4*)(s + 8);
    }
    __syncthreads();
    {
        const int d = tid >> 2, r16 = (tid & 3) * 16;
        unsigned pk[8];
        #pragma unroll
        for (int q = 0; q < 8; ++q)
            pk[q] = (unsigned)sm[r16 + 2 * q][d] | ((unsigned)sm[r16 + 2 * q + 1][d] << 16);
        u16* o = dst + ((long)b * DD + d0 + d) * TT + t0 + r16;
        *(int4*)o = int4{(int)pk[0], (int)pk[1], (int)pk[2], (int)pk[3]};
        *(int4*)(o + 8) = int4{(int)pk[4], (int)pk[5], (int)pk[6], (int)pk[7]};
    }
}

// fp32 -> bf16 weight conversion for the two FC weight matrices
__global__ __launch_bounds__(256)
void cvt_w2(const float* __restrict__ w0, u16* __restrict__ o0,
            const float* __restrict__ w1, u16* __restrict__ o1)
{
    const int i4 = (blockIdx.x * 256 + threadIdx.x) * 4;
    float4 a = *(const float4*)(w0 + i4);
    ushort4 o;
    o.x = f2bf(a.x); o.y = f2bf(a.y); o.z = f2bf(a.z); o.w = f2bf(a.w);
    *(ushort4*)(o0 + i4) = o;
    float4 b = *(const float4*)(w1 + i4);
    o.x = f2bf(b.x); o.y = f2bf(b.y); o.z = f2bf(b.z); o.w = f2bf(b.w);
    *(ushort4*)(o1 + i4) = o;
}

// ---------------------------------------------------------------------------
// LayerNorm both branches + fuse. 4 rows/block, 1 wave per row. fp32 in/out.
// ---------------------------------------------------------------------------
__global__ __launch_bounds__(256)
void ln_fuse_kernel(const float* __restrict__ yv, const float* __restrict__ ya,
                    const float* __restrict__ g, const float* __restrict__ b,
                    float* __restrict__ fuse, float* __restrict__ vpsp,
                    float* __restrict__ apsp)
{
    const long row = (long)blockIdx.x * 4 + (threadIdx.x >> 6);
    const int lane = threadIdx.x & 63;
    const float4 xv = *(const float4*)(yv + row * DD + lane * 4);
    const float4 xa = *(const float4*)(ya + row * DD + lane * 4);
    float sv = xv.x + xv.y + xv.z + xv.w;
    float sa = xa.x + xa.y + xa.z + xa.w;
    #pragma unroll
    for (int off = 32; off > 0; off >>= 1) {
        sv += __shfl_xor(sv, off);
        sa += __shfl_xor(sa, off);
    }
    const float mv = sv * (1.f / 256.f);
    const float ma = sa * (1.f / 256.f);
    const float dv0 = xv.x - mv, dv1 = xv.y - mv, dv2 = xv.z - mv, dv3 = xv.w - mv;
    const float da0 = xa.x - ma, da1 = xa.y - ma, da2 = xa.z - ma, da3 = xa.w - ma;
    float qv = dv0 * dv0 + dv1 * dv1 + dv2 * dv2 + dv3 * dv3;
    float qa = da0 * da0 + da1 * da1 + da2 * da2 + da3 * da3;
    #pragma unroll
    for (int off = 32; off > 0; off >>= 1) {
        qv += __shfl_xor(qv, off);
        qa += __shfl_xor(qa, off);
    }
    const float rv = rsqrtf(qv * (1.f / 256.f) + 1e-6f);
    const float ra = rsqrtf(qa * (1.f / 256.f) + 1e-6f);
    const float4 gg = *(const float4*)(g + lane * 4);
    const float4 bb = *(const float4*)(b + lane * 4);
    float4 ov, oa, of;
    ov.x = dv0 * rv * gg.x + bb.x; ov.y = dv1 * rv * gg.y + bb.y;
    ov.z = dv2 * rv * gg.z + bb.z; ov.w = dv3 * rv * gg.w + bb.w;
    oa.x = da0 * ra * gg.x + bb.x; oa.y = da1 * ra * gg.y + bb.y;
    oa.z = da2 * ra * gg.z + bb.z; oa.w = da3 * ra * gg.w + bb.w;
    of.x = 0.5f * (ov.x + oa.x); of.y = 0.5f * (ov.y + oa.y);
    of.z = 0.5f * (ov.z + oa.z); of.w = 0.5f * (ov.w + oa.w);
    *(float4*)(vpsp + row * DD + lane * 4) = ov;
    *(float4*)(apsp + row * DD + lane * 4) = oa;
    *(float4*)(fuse + row * DD + lane * 4) = of;
}

extern "C" void kernel_launch(void* const* d_in, const int* in_sizes, int n_in,
                              void* d_out, int out_size, void* d_ws, size_t ws_size,
                              hipStream_t stream)
{
    const float* a_fea = (const float*)d_in[0];
    const float* v_fea = (const float*)d_in[1];
    const float* thrp  = (const float*)d_in[2];
    const float* Wv1   = (const float*)d_in[3];
    const float* Wv2   = (const float*)d_in[4];
    const float* Wvfc  = (const float*)d_in[5];
    const float* Wa1   = (const float*)d_in[6];
    const float* Wa2   = (const float*)d_in[7];
    const float* Wafc  = (const float*)d_in[8];
    const float* lng   = (const float*)d_in[9];
    const float* lnb   = (const float*)d_in[10];

    const long MT = (long)NBATCH * TT;
    float* out_fuse = (float*)d_out;
    float* out_vpsp = out_fuse + MT * DD;
    float* out_apsp = out_vpsp + MT * DD;
    float* out_pred = out_apsp + MT * DD;

    // workspace layout (bf16 feature arrays are MT*DD*2 = 8.39 MB each):
    //   v2h v2l a1h a1l v1b a2b v1T a2T | rs cs rst cst | Wfcb x2 | beta,Pva,PavT xG
    // aliases: yv(f32) over v2h+v2l; ya over a1h+a1l; yvin(bf16) over v1b; yain over a2b
    char* ws = (char*)d_ws;
    const size_t fb = (size_t)MT * DD * sizeof(u16);   // 8388608
    const size_t sumB = (size_t)MT * sizeof(float);    // 65536
    u16* v2h = (u16*)(ws + 0 * fb);
    u16* v2l = (u16*)(ws + 1 * fb);
    u16* a1h = (u16*)(ws + 2 * fb);
    u16* a1l = (u16*)(ws + 3 * fb);
    u16* v1b = (u16*)(ws + 4 * fb);
    u16* a2b = (u16*)(ws + 5 * fb);
    u16* v1T = (u16*)(ws + 6 * fb);
    u16* a2T = (u16*)(ws + 7 * fb);
    char* p = ws + 8 * fb;
    float* rs  = (float*)(p + 0 * sumB);
    float* cs  = (float*)(p + 1 * sumB);
    float* rst = (float*)(p + 2 * sumB);
    float* cst = (float*)(p + 3 * sumB);
    u16* Wvfcb = (u16*)(p + 4 * sumB);
    u16* Wafcb = Wvfcb + DD * DD;
    char* q = p + 4 * sumB + 2 * DD * DD * sizeof(u16);
    const size_t betaB = (size_t)TT * TT * sizeof(float);  // 16.78 MB
    const size_t pB = (size_t)TT * TT * sizeof(u16);       // 8.39 MB
    const size_t fixed = (size_t)(q - ws);
    int G = 1;
    if (ws_size > fixed + (betaB + 2 * pB)) {
        size_t gmax = (ws_size - fixed) / (betaB + 2 * pB);
        G = (int)(gmax > NBATCH ? NBATCH : gmax);
        if (G < 1) G = 1;
    }
    float* beta = (float*)q;
    u16* Pva  = (u16*)(q + (size_t)G * betaB);
    u16* PavT = Pva + (size_t)G * TT * TT;
    // fp32 aliases for FC outputs
    float* yv = (float*)(ws + 0 * fb);   // over v2h+v2l
    float* ya = (float*)(ws + 2 * fb);   // over a1h+a1l
    u16* yvin = v1b;                     // PV output (+resid), bf16
    u16* yain = a2b;

    hipMemsetAsync(rs, 0, 4 * sumB, stream);

    const dim3 blk(256, 1, 1);

    // exact fp32 projections; epilogues emit bf16 (split h/l for score inputs)
    gemm_nt<<<dim3(DD / 64, MT / 64, 1), blk, 0, stream>>>(
        v_fea, Wv2, nullptr, v2h, v2l, (int)MT, DD, DD, 1.f, 1);
    gemm_nt<<<dim3(DD / 64, MT / 64, 1), blk, 0, stream>>>(
        a_fea, Wa1, nullptr, a1h, a1l, (int)MT, DD, DD, 1.f, 1);
    gemm_nt<<<dim3(DD / 64, MT / 64, 1), blk, 0, stream>>>(
        v_fea, Wv1, nullptr, v1b, nullptr, (int)MT, DD, DD, 1.f, 2);
    gemm_nt<<<dim3(DD / 64, MT / 64, 1), blk, 0, stream>>>(
        a_fea, Wa2, nullptr, a2b, nullptr, (int)MT, DD, DD, 1.f, 2);
    cvt_w2<<<dim3(DD * DD / 1024, 1, 1), blk, 0, stream>>>(Wvfc, Wvfcb, Wafc, Wafcb);
    transpose2<<<dim3(DD / 64, TT / 64, 16), blk, 0, stream>>>(v1b, v1T, a2b, a2T);

    for (int g0 = 0; g0 < NBATCH; g0 += G) {
        const int g = (NBATCH - g0 < G) ? (NBATCH - g0) : G;
        // beta = relu(v2·a1 / 16), split-bf16 4-term MFMA (err ~1e-5 rel)
        mfma_nt<4, 128, 128, 0><<<dim3(TT / 128, TT / 128, g), blk, 0, stream>>>(
            v2h + (long)g0 * TT * DD, v2l + (long)g0 * TT * DD,
            a1h + (long)g0 * TT * DD, a1l + (long)g0 * TT * DD,
            beta, nullptr, nullptr, nullptr, nullptr,
            TT, TT, DD, DD, DD,
            (long)TT * DD, (long)TT * DD, (long)TT * TT, 1.f / 16.f);
        sums_kernel<<<dim3(TT / 64, TT / 64, g), blk, 0, stream>>>(beta, rs, cs, g0);
        if (g0 == 0)
            pred_exact<<<dim3(TT / 8, 1, 1), blk, 0, stream>>>(
                v_fea, a_fea, Wv2, Wa1, cs, thrp, out_pred);
        sums_thr_ext<<<dim3(TT / 64, TT / 64, g), blk, 0, stream>>>(
            beta, rs, cs, rst, cst, thrp, Pva, PavT, g0);
        // yvin = v_fea + g_va @ a2   (bf16 out, renorm+residual fused)
        mfma_nt<1, 64, 256, 1><<<dim3(1, TT / 64, g), blk, 0, stream>>>(
            Pva, nullptr, a2T + (long)g0 * DD * TT, nullptr,
            nullptr, yvin + (long)g0 * TT * DD, v_fea + (long)g0 * TT * DD,
            rs + (long)g0 * TT, rst + (long)g0 * TT,
            TT, DD, TT, TT, TT,
            (long)TT * TT, (long)DD * TT, (long)TT * DD, 1.f);
        // yain = a_fea + g_av @ v1
        mfma_nt<1, 64, 256, 1><<<dim3(1, TT / 64, g), blk, 0, stream>>>(
            PavT, nullptr, v1T + (long)g0 * DD * TT, nullptr,
            nullptr, yain + (long)g0 * TT * DD, a_fea + (long)g0 * TT * DD,
            cs + (long)g0 * TT, cst + (long)g0 * TT,
            TT, DD, TT, TT, TT,
            (long)TT * TT, (long)DD * TT, (long)TT * DD, 1.f);
    }

    // FC: yv = relu(yvin @ Wvfc^T) fp32 (bf16 MFMA), then LN+fuse
    mfma_nt<1, 128, 128, 0><<<dim3(DD / 128, MT / 128, 1), blk, 0, stream>>>(
        yvin, nullptr, Wvfcb, nullptr, yv, nullptr, nullptr, nullptr, nullptr,
        (int)MT, DD, DD, DD, DD, 0, 0, 0, 1.f);
    mfma_nt<1, 128, 128, 0><<<dim3(DD / 128, MT / 128, 1), blk, 0, stream>>>(
        yain, nullptr, Wafcb, nullptr, ya, nullptr, nullptr, nullptr, nullptr,
        (int)MT, DD, DD, DD, DD, 0, 0, 0, 1.f);
    ln_fuse_kernel<<<dim3(MT / 4, 1, 1), blk, 0, stream>>>(
        yv, ya, lng, lnb, out_fuse, out_vpsp, out_apsp);
}

// Round 3
// 596.737 us; speedup vs baseline: 1.8537x; 1.2235x over previous
//
#include <hip/hip_runtime.h>
#include <math.h>

#define TT 2048
#define DD 256
#define NBATCH 8
#define EPSF 1e-8f

typedef unsigned short u16;
typedef __attribute__((ext_vector_type(8))) short short8;
typedef __attribute__((ext_vector_type(4))) float f32x4;

__device__ __forceinline__ u16 f2bf(float x) {
    unsigned int u = __builtin_bit_cast(unsigned int, x);
    u += 0x7fffu + ((u >> 16) & 1u);
    return (u16)(u >> 16);
}
__device__ __forceinline__ float bf2f(u16 h) {
    return __builtin_bit_cast(float, (unsigned int)h << 16);
}

// ---------------------------------------------------------------------------
// Stage a [BR rows x 32 k] bf16 tile from global ([row][k], k contig) into LDS
// in MFMA-fragment order: elem(row,k) -> (((row>>4)*4+(k>>3))*16+(row&15))*8+(k&7)
// Fragment read for 16-row tile t = ds_read_b128 at (t*64+lane)*8 elems.
// ---------------------------------------------------------------------------
template<int BR>
__device__ __forceinline__ void stage_tile(const u16* __restrict__ g, u16* s,
                                           int row0, int k0, int ldk, int tid)
{
    #pragma unroll
    for (int i = 0; i < BR / 64; ++i) {
        const int c = tid + 256 * i;
        const int row = c >> 2, q = c & 3;
        const int dst = (((row >> 4) * 4 + q) * 16 + (row & 15)) * 8;
        *(int4*)(s + dst) = *(const int4*)(g + (long)(row0 + row) * ldk + k0 + q * 8);
    }
}

// ---------------------------------------------------------------------------
// bf16 MFMA NT GEMM. A [m][k], B [n][k], 256 thr = 4 waves (WROWS x WCOLS).
// NTERM=4: split h/l inputs, 4 chained MFMAs (near-fp32, ~1e-5 rel).
// EPI=0: Cf = relu(acc*scale) fp32                       [FC]
// EPI=1: Cb = bf16(acc*inv[m] + resid), inv from rst/rs  [PV renorm+residual]
// EPI=2: Cf = relu(acc*scale); atomicAdd row sums->rs_out, col sums->cs_out
//                                                        [scores + sums fusion]
// EPI=3: relu -> split bf16 (Cb=h, Cb2=l)                [proj v2/a1]
// EPI=4: relu -> bf16 (Cb)                               [proj v1/a2]
// ---------------------------------------------------------------------------
template<int NTERM, int BM, int BN, int WROWS, int WCOLS, int EPI>
__global__ __launch_bounds__(256)
void mfma_nt(const u16* __restrict__ Ah, const u16* __restrict__ Al,
             const u16* __restrict__ Bh, const u16* __restrict__ Bl,
             float* __restrict__ Cf, u16* __restrict__ Cb, u16* __restrict__ Cb2,
             const float* __restrict__ resid,
             const float* __restrict__ sum_all, const float* __restrict__ sum_thr,
             float* __restrict__ rs_out, float* __restrict__ cs_out,
             int M, int N, int K, int lda, int ldb,
             long sAz, long sBz, long sCz, float scale, int batch0)
{
    constexpr int WM = BM / (16 * WROWS);
    constexpr int WN = BN / (16 * WCOLS);
    __shared__ __align__(16) u16 Ah_s[BM * 32];
    __shared__ __align__(16) u16 Bh_s[BN * 32];
    __shared__ __align__(16) u16 Al_s[NTERM == 4 ? BM * 32 : 8];
    __shared__ __align__(16) u16 Bl_s[NTERM == 4 ? BN * 32 : 8];
    const int z = blockIdx.z;
    const int m0 = blockIdx.y * BM, n0 = blockIdx.x * BN;
    const int tid = threadIdx.x;
    const int lane = tid & 63, w = tid >> 6;
    const int wy = w / WCOLS, wx = w % WCOLS;
    f32x4 acc[WM][WN] = {};

    for (int k0 = 0; k0 < K; k0 += 32) {
        stage_tile<BM>(Ah + (long)z * sAz, Ah_s, m0, k0, lda, tid);
        stage_tile<BN>(Bh + (long)z * sBz, Bh_s, n0, k0, ldb, tid);
        if (NTERM == 4) {
            stage_tile<BM>(Al + (long)z * sAz, Al_s, m0, k0, lda, tid);
            stage_tile<BN>(Bl + (long)z * sBz, Bl_s, n0, k0, ldb, tid);
        }
        __syncthreads();
        short8 ah[WM], bh[WN], al[WM], bl[WN];
        #pragma unroll
        for (int i = 0; i < WM; ++i) {
            ah[i] = *(const short8*)(Ah_s + ((wy * WM + i) * 64 + lane) * 8);
            if (NTERM == 4)
                al[i] = *(const short8*)(Al_s + ((wy * WM + i) * 64 + lane) * 8);
        }
        #pragma unroll
        for (int j = 0; j < WN; ++j) {
            bh[j] = *(const short8*)(Bh_s + ((wx * WN + j) * 64 + lane) * 8);
            if (NTERM == 4)
                bl[j] = *(const short8*)(Bl_s + ((wx * WN + j) * 64 + lane) * 8);
        }
        #pragma unroll
        for (int i = 0; i < WM; ++i)
            #pragma unroll
            for (int j = 0; j < WN; ++j) {
                if (NTERM == 4) {
                    acc[i][j] = __builtin_amdgcn_mfma_f32_16x16x32_bf16(al[i], bl[j], acc[i][j], 0, 0, 0);
                    acc[i][j] = __builtin_amdgcn_mfma_f32_16x16x32_bf16(al[i], bh[j], acc[i][j], 0, 0, 0);
                    acc[i][j] = __builtin_amdgcn_mfma_f32_16x16x32_bf16(ah[i], bl[j], acc[i][j], 0, 0, 0);
                }
                acc[i][j] = __builtin_amdgcn_mfma_f32_16x16x32_bf16(ah[i], bh[j], acc[i][j], 0, 0, 0);
            }
        __syncthreads();
    }

    // C/D layout: col=lane&15, row=(lane>>4)*4+reg  [m89/m91 verified]
    const int quad = lane >> 4, col = lane & 15;
    if (EPI == 2) {
        #pragma unroll
        for (int i = 0; i < WM; ++i)
            #pragma unroll
            for (int j = 0; j < WN; ++j)
                #pragma unroll
                for (int r = 0; r < 4; ++r) {
                    float v = fmaxf(acc[i][j][r] * scale, 0.f);
                    acc[i][j][r] = v;
                    const int row = m0 + (wy * WM + i) * 16 + quad * 4 + r;
                    const int c = n0 + (wx * WN + j) * 16 + col;
                    Cf[(long)z * sCz + (long)row * N + c] = v;
                }
        #pragma unroll
        for (int i = 0; i < WM; ++i)
            #pragma unroll
            for (int r = 0; r < 4; ++r) {
                float rp = 0.f;
                #pragma unroll
                for (int j = 0; j < WN; ++j) rp += acc[i][j][r];
                rp += __shfl_xor(rp, 1); rp += __shfl_xor(rp, 2);
                rp += __shfl_xor(rp, 4); rp += __shfl_xor(rp, 8);
                if (col == 0) {
                    const int row = m0 + (wy * WM + i) * 16 + quad * 4 + r;
                    atomicAdd(&rs_out[(long)(batch0 + z) * TT + row], rp);
                }
            }
        #pragma unroll
        for (int j = 0; j < WN; ++j) {
            float cp = 0.f;
            #pragma unroll
            for (int i = 0; i < WM; ++i)
                #pragma unroll
                for (int r = 0; r < 4; ++r) cp += acc[i][j][r];
            cp += __shfl_xor(cp, 16); cp += __shfl_xor(cp, 32);
            if (lane < 16) {
                const int c = n0 + (wx * WN + j) * 16 + col;
                atomicAdd(&cs_out[(long)(batch0 + z) * TT + c], cp);
            }
        }
        return;
    }
    #pragma unroll
    for (int i = 0; i < WM; ++i) {
        const int rbase = m0 + (wy * WM + i) * 16 + quad * 4;
        #pragma unroll
        for (int j = 0; j < WN; ++j) {
            const int c = n0 + (wx * WN + j) * 16 + col;
            #pragma unroll
            for (int r = 0; r < 4; ++r) {
                const int row = rbase + r;
                float v = acc[i][j][r];
                if (EPI == 0) {
                    Cf[(long)z * sCz + (long)row * N + c] = fmaxf(v * scale, 0.f);
                } else if (EPI == 1) {
                    const float sa = sum_all[(long)z * TT + row];
                    const float st = sum_thr[(long)z * TT + row];
                    const float inv = 1.0f / (st + EPSF * (sa + EPSF));
                    v = v * inv + resid[(long)z * sCz + (long)row * N + c];
                    Cb[(long)z * sCz + (long)row * N + c] = f2bf(v);
                } else if (EPI == 3) {
                    v = fmaxf(v * scale, 0.f);
                    const u16 h = f2bf(v);
                    Cb[(long)row * N + c] = h;
                    Cb2[(long)row * N + c] = f2bf(v - bf2f(h));
                } else { // EPI == 4
                    v = fmaxf(v * scale, 0.f);
                    Cb[(long)row * N + c] = f2bf(v);
                }
            }
        }
    }
}

// ---------------------------------------------------------------------------
// Thresholded row/col sums + emission of pass matrices as bf16:
//   Pva [t][s] = beta[t][s]  if > thr*(rs[t]+EPS)  else 0
//   PavT[t][s] = beta[s][t]  if > thr*(cs[t]+EPS)  else 0   (transposed)
// ---------------------------------------------------------------------------
__global__ __launch_bounds__(256)
void sums_thr_ext(const float* __restrict__ beta, const float* __restrict__ rs,
                  const float* __restrict__ cs, float* __restrict__ rst,
                  float* __restrict__ cst, const float* __restrict__ thrp,
                  u16* __restrict__ Pva, u16* __restrict__ PavT, int batch0)
{
    __shared__ float sm[64][65];
    __shared__ float rthr[64], cthr[64];
    const int z = blockIdx.z;
    const float* Bt = beta + (long)z * TT * TT;
    const int r0 = blockIdx.y * 64, c0 = blockIdx.x * 64;
    const int tid = threadIdx.x;
    const int rbase = tid >> 4;
    const int c4 = (tid & 15) << 2;
    #pragma unroll
    for (int rr = 0; rr < 4; ++rr) {
        int r = rbase + rr * 16;
        float4 v = *(const float4*)(Bt + (long)(r0 + r) * TT + c0 + c4);
        sm[r][c4 + 0] = v.x; sm[r][c4 + 1] = v.y;
        sm[r][c4 + 2] = v.z; sm[r][c4 + 3] = v.w;
    }
    const float thr = thrp[0] * 10.0f / (float)TT;
    const int b = batch0 + z;
    if (tid < 64)
        rthr[tid] = thr * (rs[(long)b * TT + r0 + tid] + EPSF);
    else if (tid < 128)
        cthr[tid - 64] = thr * (cs[(long)b * TT + c0 + tid - 64] + EPSF);
    __syncthreads();
    if (tid < 64) {
        const float ct = rthr[tid];
        float s = 0.f;
        #pragma unroll 8
        for (int k = 0; k < 64; ++k) {
            float v = sm[tid][k];
            if (v > ct) s += v;
        }
        atomicAdd(&rst[(long)b * TT + r0 + tid], s);
    } else if (tid < 128) {
        int c = tid - 64;
        const float ct = cthr[c];
        float s = 0.f;
        #pragma unroll 8
        for (int k = 0; k < 64; ++k) {
            float v = sm[k][c];
            if (v > ct) s += v;
        }
        atomicAdd(&cst[(long)b * TT + c0 + c], s);
    }
    {   // Pva: row-thresholded, natural layout
        const int r = tid >> 2, c16 = (tid & 3) * 16;
        const float ct = rthr[r];
        unsigned pk[8];
        #pragma unroll
        for (int q = 0; q < 8; ++q) {
            float v0 = sm[r][c16 + 2 * q];
            float v1 = sm[r][c16 + 2 * q + 1];
            v0 = (v0 > ct) ? v0 : 0.f;
            v1 = (v1 > ct) ? v1 : 0.f;
            pk[q] = (unsigned)f2bf(v0) | ((unsigned)f2bf(v1) << 16);
        }
        u16* dst = Pva + (long)z * TT * TT + (long)(r0 + r) * TT + c0 + c16;
        *(int4*)dst = int4{(int)pk[0], (int)pk[1], (int)pk[2], (int)pk[3]};
        *(int4*)(dst + 8) = int4{(int)pk[4], (int)pk[5], (int)pk[6], (int)pk[7]};
    }
    {   // PavT: col-thresholded, transposed
        const int c = tid >> 2, r16 = (tid & 3) * 16;
        const float ct = cthr[c];
        unsigned pk[8];
        #pragma unroll
        for (int q = 0; q < 8; ++q) {
            float v0 = sm[r16 + 2 * q][c];
            float v1 = sm[r16 + 2 * q + 1][c];
            v0 = (v0 > ct) ? v0 : 0.f;
            v1 = (v1 > ct) ? v1 : 0.f;
            pk[q] = (unsigned)f2bf(v0) | ((unsigned)f2bf(v1) << 16);
        }
        u16* dst = PavT + (long)z * TT * TT + (long)(c0 + c) * TT + r0 + r16;
        *(int4*)dst = int4{(int)pk[0], (int)pk[1], (int)pk[2], (int)pk[3]};
        *(int4*)(dst + 8) = int4{(int)pk[4], (int)pk[5], (int)pk[6], (int)pk[7]};
    }
}

// ---------------------------------------------------------------------------
// Exact fp32 pred: recompute v2[0,t], a1[0,t] and their dot; compare.
// ---------------------------------------------------------------------------
__global__ __launch_bounds__(256)
void pred_exact(const float* __restrict__ vf, const float* __restrict__ af,
                const float* __restrict__ Wv2, const float* __restrict__ Wa1,
                const float* __restrict__ cs, const float* __restrict__ thrp,
                float* __restrict__ pred)
{
    __shared__ float vs[8][260];
    __shared__ float as_[8][260];
    __shared__ float red[4][8];
    const int t0 = blockIdx.x * 8;
    const int tid = threadIdx.x;
    {
        const int i = tid >> 5, c = (tid & 31) * 8;
        *(float4*)&vs[i][c] = *(const float4*)(vf + (long)(t0 + i) * DD + c);
        *(float4*)&vs[i][c + 4] = *(const float4*)(vf + (long)(t0 + i) * DD + c + 4);
        *(float4*)&as_[i][c] = *(const float4*)(af + (long)(t0 + i) * DD + c);
        *(float4*)&as_[i][c + 4] = *(const float4*)(af + (long)(t0 + i) * DD + c + 4);
    }
    __syncthreads();
    const int j = tid;
    float av[8] = {0.f}, aa[8] = {0.f};
    for (int k = 0; k < DD; k += 4) {
        const float4 wv = *(const float4*)(Wv2 + (long)j * DD + k);
        const float4 wa = *(const float4*)(Wa1 + (long)j * DD + k);
        #pragma unroll
        for (int i = 0; i < 8; ++i) {
            const float4 x = *(const float4*)&vs[i][k];
            av[i] += wv.x * x.x + wv.y * x.y + wv.z * x.z + wv.w * x.w;
            const float4 y = *(const float4*)&as_[i][k];
            aa[i] += wa.x * y.x + wa.y * y.y + wa.z * y.z + wa.w * y.w;
        }
    }
    float p[8];
    #pragma unroll
    for (int i = 0; i < 8; ++i)
        p[i] = fmaxf(av[i], 0.f) * fmaxf(aa[i], 0.f);
    #pragma unroll
    for (int off = 32; off > 0; off >>= 1)
        #pragma unroll
        for (int i = 0; i < 8; ++i) p[i] += __shfl_xor(p[i], off);
    const int lane = tid & 63, wv_ = tid >> 6;
    if (lane == 0)
        #pragma unroll
        for (int i = 0; i < 8; ++i) red[wv_][i] = p[i];
    __syncthreads();
    if (tid < 8) {
        float d = red[0][tid] + red[1][tid] + red[2][tid] + red[3][tid];
        d = fmaxf(d * (1.f / 16.f), 0.f);
        const float thr = thrp[0] * 10.0f / (float)TT;
        pred[t0 + tid] = (d > thr * (cs[t0 + tid] + EPSF)) ? 1.0f : 0.0f;
    }
}

// ---------------------------------------------------------------------------
// Batch transpose bf16: [8][2048][256] -> [8][256][2048]; z<8: v1, z>=8: a2.
// ---------------------------------------------------------------------------
__global__ __launch_bounds__(256)
void transpose2(const u16* __restrict__ v1b, u16* __restrict__ v1T,
                const u16* __restrict__ a2b, u16* __restrict__ a2T)
{
    __shared__ u16 sm[64][72];
    const int zz = blockIdx.z;
    const u16* src = (zz < 8) ? v1b : a2b;
    u16* dst = (zz < 8) ? v1T : a2T;
    const int b = zz & 7;
    const int t0 = blockIdx.y * 64, d0 = blockIdx.x * 64;
    const int tid = threadIdx.x;
    {
        const int r = tid >> 2, c16 = (tid & 3) * 16;
        const u16* s = src + ((long)b * TT + t0 + r) * DD + d0 + c16;
        *(int4*)&sm[r][c16] = *(const int4*)s;
        *(int4*)&sm[r][c16 + 8] = *(const int4*)(s + 8);
    }
    __syncthreads();
    {
        const int d = tid >> 2, r16 = (tid & 3) * 16;
        unsigned pk[8];
        #pragma unroll
        for (int q = 0; q < 8; ++q)
            pk[q] = (unsigned)sm[r16 + 2 * q][d] | ((unsigned)sm[r16 + 2 * q + 1][d] << 16);
        u16* o = dst + ((long)b * DD + d0 + d) * TT + t0 + r16;
        *(int4*)o = int4{(int)pk[0], (int)pk[1], (int)pk[2], (int)pk[3]};
        *(int4*)(o + 8) = int4{(int)pk[4], (int)pk[5], (int)pk[6], (int)pk[7]};
    }
}

// ---------------------------------------------------------------------------
// Split v_fea/a_fea fp32 -> bf16 h/l pairs. grid.y: 0=v, 1=a.
// ---------------------------------------------------------------------------
__global__ __launch_bounds__(256)
void split_feat(const float* __restrict__ vf, const float* __restrict__ af,
                u16* __restrict__ vfh, u16* __restrict__ vfl,
                u16* __restrict__ afh, u16* __restrict__ afl)
{
    const long i4 = ((long)blockIdx.x * 256 + threadIdx.x) * 4;
    const float* src = blockIdx.y ? af : vf;
    u16* dh = blockIdx.y ? afh : vfh;
    u16* dl = blockIdx.y ? afl : vfl;
    float4 a = *(const float4*)(src + i4);
    ushort4 h4, l4; u16 h;
    h = f2bf(a.x); h4.x = h; l4.x = f2bf(a.x - bf2f(h));
    h = f2bf(a.y); h4.y = h; l4.y = f2bf(a.y - bf2f(h));
    h = f2bf(a.z); h4.z = h; l4.z = f2bf(a.z - bf2f(h));
    h = f2bf(a.w); h4.w = h; l4.w = f2bf(a.w - bf2f(h));
    *(ushort4*)(dh + i4) = h4;
    *(ushort4*)(dl + i4) = l4;
}

// ---------------------------------------------------------------------------
// Split/convert 6 weight matrices. out layout: [Wv1h Wv1l Wv2h Wv2l Wa1h Wa1l
// Wa2h Wa2l Wvfcb Wafcb], each DD*DD. grid.y = task 0..5.
// ---------------------------------------------------------------------------
__global__ __launch_bounds__(256)
void split_w(const float* __restrict__ w0, const float* __restrict__ w1,
             const float* __restrict__ w2, const float* __restrict__ w3,
             const float* __restrict__ w4, const float* __restrict__ w5,
             u16* __restrict__ out)
{
    const int t = blockIdx.y;
    const float* w = (t == 0) ? w0 : (t == 1) ? w1 : (t == 2) ? w2
                   : (t == 3) ? w3 : (t == 4) ? w4 : w5;
    const int i4 = (blockIdx.x * 256 + threadIdx.x) * 4;
    float4 a = *(const float4*)(w + i4);
    if (t < 4) {
        u16* oh = out + (size_t)t * 2 * DD * DD;
        u16* ol = oh + DD * DD;
        ushort4 h4, l4; u16 h;
        h = f2bf(a.x); h4.x = h; l4.x = f2bf(a.x - bf2f(h));
        h = f2bf(a.y); h4.y = h; l4.y = f2bf(a.y - bf2f(h));
        h = f2bf(a.z); h4.z = h; l4.z = f2bf(a.z - bf2f(h));
        h = f2bf(a.w); h4.w = h; l4.w = f2bf(a.w - bf2f(h));
        *(ushort4*)(oh + i4) = h4;
        *(ushort4*)(ol + i4) = l4;
    } else {
        u16* ob = out + (size_t)8 * DD * DD + (size_t)(t - 4) * DD * DD;
        ushort4 o;
        o.x = f2bf(a.x); o.y = f2bf(a.y); o.z = f2bf(a.z); o.w = f2bf(a.w);
        *(ushort4*)(ob + i4) = o;
    }
}

// ---------------------------------------------------------------------------
// LayerNorm both branches + fuse. 4 rows/block, 1 wave per row. fp32 in/out.
// ---------------------------------------------------------------------------
__global__ __launch_bounds__(256)
void ln_fuse_kernel(const float* __restrict__ yv, const float* __restrict__ ya,
                    const float* __restrict__ g, const float* __restrict__ b,
                    float* __restrict__ fuse, float* __restrict__ vpsp,
                    float* __restrict__ apsp)
{
    const long row = (long)blockIdx.x * 4 + (threadIdx.x >> 6);
    const int lane = threadIdx.x & 63;
    const float4 xv = *(const float4*)(yv + row * DD + lane * 4);
    const float4 xa = *(const float4*)(ya + row * DD + lane * 4);
    float sv = xv.x + xv.y + xv.z + xv.w;
    float sa = xa.x + xa.y + xa.z + xa.w;
    #pragma unroll
    for (int off = 32; off > 0; off >>= 1) {
        sv += __shfl_xor(sv, off);
        sa += __shfl_xor(sa, off);
    }
    const float mv = sv * (1.f / 256.f);
    const float ma = sa * (1.f / 256.f);
    const float dv0 = xv.x - mv, dv1 = xv.y - mv, dv2 = xv.z - mv, dv3 = xv.w - mv;
    const float da0 = xa.x - ma, da1 = xa.y - ma, da2 = xa.z - ma, da3 = xa.w - ma;
    float qv = dv0 * dv0 + dv1 * dv1 + dv2 * dv2 + dv3 * dv3;
    float qa = da0 * da0 + da1 * da1 + da2 * da2 + da3 * da3;
    #pragma unroll
    for (int off = 32; off > 0; off >>= 1) {
        qv += __shfl_xor(qv, off);
        qa += __shfl_xor(qa, off);
    }
    const float rv = rsqrtf(qv * (1.f / 256.f) + 1e-6f);
    const float ra = rsqrtf(qa * (1.f / 256.f) + 1e-6f);
    const float4 gg = *(const float4*)(g + lane * 4);
    const float4 bb = *(const float4*)(b + lane * 4);
    float4 ov, oa, of;
    ov.x = dv0 * rv * gg.x + bb.x; ov.y = dv1 * rv * gg.y + bb.y;
    ov.z = dv2 * rv * gg.z + bb.z; ov.w = dv3 * rv * gg.w + bb.w;
    oa.x = da0 * ra * gg.x + bb.x; oa.y = da1 * ra * gg.y + bb.y;
    oa.z = da2 * ra * gg.z + bb.z; oa.w = da3 * ra * gg.w + bb.w;
    of.x = 0.5f * (ov.x + oa.x); of.y = 0.5f * (ov.y + oa.y);
    of.z = 0.5f * (ov.z + oa.z); of.w = 0.5f * (ov.w + oa.w);
    *(float4*)(vpsp + row * DD + lane * 4) = ov;
    *(float4*)(apsp + row * DD + lane * 4) = oa;
    *(float4*)(fuse + row * DD + lane * 4) = of;
}

extern "C" void kernel_launch(void* const* d_in, const int* in_sizes, int n_in,
                              void* d_out, int out_size, void* d_ws, size_t ws_size,
                              hipStream_t stream)
{
    const float* a_fea = (const float*)d_in[0];
    const float* v_fea = (const float*)d_in[1];
    const float* thrp  = (const float*)d_in[2];
    const float* Wv1   = (const float*)d_in[3];
    const float* Wv2   = (const float*)d_in[4];
    const float* Wvfc  = (const float*)d_in[5];
    const float* Wa1   = (const float*)d_in[6];
    const float* Wa2   = (const float*)d_in[7];
    const float* Wafc  = (const float*)d_in[8];
    const float* lng   = (const float*)d_in[9];
    const float* lnb   = (const float*)d_in[10];

    const long MT = (long)NBATCH * TT;
    float* out_fuse = (float*)d_out;
    float* out_vpsp = out_fuse + MT * DD;
    float* out_apsp = out_vpsp + MT * DD;
    float* out_pred = out_apsp + MT * DD;

    // ws: v2h v2l a1h a1l v1b a2b v1T a2T | rs cs rst cst | Wsplit(10) | group
    // group region (G x 33.55MB) also hosts the transient feature splits
    // (vfh vfl afh afl = 33.55MB, dead before the first score write).
    char* ws = (char*)d_ws;
    const size_t fb = (size_t)MT * DD * sizeof(u16);
    const size_t sumB = (size_t)MT * sizeof(float);
    u16* v2h = (u16*)(ws + 0 * fb);
    u16* v2l = (u16*)(ws + 1 * fb);
    u16* a1h = (u16*)(ws + 2 * fb);
    u16* a1l = (u16*)(ws + 3 * fb);
    u16* v1b = (u16*)(ws + 4 * fb);
    u16* a2b = (u16*)(ws + 5 * fb);
    u16* v1T = (u16*)(ws + 6 * fb);
    u16* a2T = (u16*)(ws + 7 * fb);
    char* p = ws + 8 * fb;
    float* rs  = (float*)(p + 0 * sumB);
    float* cs  = (float*)(p + 1 * sumB);
    float* rst = (float*)(p + 2 * sumB);
    float* cst = (float*)(p + 3 * sumB);
    u16* Wsp = (u16*)(p + 4 * sumB);           // 10 x DD*DD
    u16* Wv1h = Wsp + 0 * DD * DD;  u16* Wv1l = Wsp + 1 * DD * DD;
    u16* Wv2h = Wsp + 2 * DD * DD;  u16* Wv2l = Wsp + 3 * DD * DD;
    u16* Wa1h = Wsp + 4 * DD * DD;  u16* Wa1l = Wsp + 5 * DD * DD;
    u16* Wa2h = Wsp + 6 * DD * DD;  u16* Wa2l = Wsp + 7 * DD * DD;
    u16* Wvfcb = Wsp + 8 * DD * DD; u16* Wafcb = Wsp + 9 * DD * DD;
    char* q = p + 4 * sumB + 10 * DD * DD * sizeof(u16);
    const size_t betaB = (size_t)TT * TT * sizeof(float);
    const size_t pB = (size_t)TT * TT * sizeof(u16);
    const size_t fixed = (size_t)(q - ws);
    int G = 1;
    if (ws_size > fixed + (betaB + 2 * pB)) {
        size_t gmax = (ws_size - fixed) / (betaB + 2 * pB);
        G = (int)(gmax > NBATCH ? NBATCH : gmax);
        if (G < 1) G = 1;
    }
    float* beta = (float*)q;
    u16* Pva  = (u16*)(q + (size_t)G * betaB);
    u16* PavT = Pva + (size_t)G * TT * TT;
    // transient feature splits live in the group region (== 4*fb min size)
    u16* vfh = (u16*)q;
    u16* vfl = vfh + MT * DD;
    u16* afh = vfl + MT * DD;
    u16* afl = afh + MT * DD;
    // fp32 aliases for FC outputs (over dead proj arrays)
    float* yv = (float*)(ws + 0 * fb);
    float* ya = (float*)(ws + 2 * fb);
    u16* yvin = v1b;
    u16* yain = a2b;

    hipMemsetAsync(rs, 0, 4 * sumB, stream);

    const dim3 blk(256, 1, 1);

    // input splits
    split_feat<<<dim3((unsigned)(MT * DD / 1024), 2, 1), blk, 0, stream>>>(
        v_fea, a_fea, vfh, vfl, afh, afl);
    split_w<<<dim3(DD * DD / 1024, 6, 1), blk, 0, stream>>>(
        Wv1, Wv2, Wa1, Wa2, Wvfc, Wafc, Wsp);

    // projections: 4-term split-bf16 MFMA (~1e-5 rel)
    mfma_nt<4, 64, 64, 2, 2, 3><<<dim3(DD / 64, (unsigned)(MT / 64), 1), blk, 0, stream>>>(
        vfh, vfl, Wv2h, Wv2l, nullptr, v2h, v2l, nullptr, nullptr, nullptr,
        nullptr, nullptr, (int)MT, DD, DD, DD, DD, 0, 0, 0, 1.f, 0);
    mfma_nt<4, 64, 64, 2, 2, 3><<<dim3(DD / 64, (unsigned)(MT / 64), 1), blk, 0, stream>>>(
        afh, afl, Wa1h, Wa1l, nullptr, a1h, a1l, nullptr, nullptr, nullptr,
        nullptr, nullptr, (int)MT, DD, DD, DD, DD, 0, 0, 0, 1.f, 0);
    mfma_nt<4, 64, 64, 2, 2, 4><<<dim3(DD / 64, (unsigned)(MT / 64), 1), blk, 0, stream>>>(
        vfh, vfl, Wv1h, Wv1l, nullptr, v1b, nullptr, nullptr, nullptr, nullptr,
        nullptr, nullptr, (int)MT, DD, DD, DD, DD, 0, 0, 0, 1.f, 0);
    mfma_nt<4, 64, 64, 2, 2, 4><<<dim3(DD / 64, (unsigned)(MT / 64), 1), blk, 0, stream>>>(
        afh, afl, Wa2h, Wa2l, nullptr, a2b, nullptr, nullptr, nullptr, nullptr,
        nullptr, nullptr, (int)MT, DD, DD, DD, DD, 0, 0, 0, 1.f, 0);
    transpose2<<<dim3(DD / 64, TT / 64, 16), blk, 0, stream>>>(v1b, v1T, a2b, a2T);

    for (int g0 = 0; g0 < NBATCH; g0 += G) {
        const int g = (NBATCH - g0 < G) ? (NBATCH - g0) : G;
        // beta = relu(v2.a1/16), fp32 out + fused rs/cs atomics
        mfma_nt<4, 128, 128, 2, 2, 2><<<dim3(TT / 128, TT / 128, g), blk, 0, stream>>>(
            v2h + (long)g0 * TT * DD, v2l + (long)g0 * TT * DD,
            a1h + (long)g0 * TT * DD, a1l + (long)g0 * TT * DD,
            beta, nullptr, nullptr, nullptr, nullptr, nullptr,
            rs, cs, TT, TT, DD, DD, DD,
            (long)TT * DD, (long)TT * DD, (long)TT * TT, 1.f / 16.f, g0);
        if (g0 == 0)
            pred_exact<<<dim3(TT / 8, 1, 1), blk, 0, stream>>>(
                v_fea, a_fea, Wv2, Wa1, cs, thrp, out_pred);
        sums_thr_ext<<<dim3(TT / 64, TT / 64, g), blk, 0, stream>>>(
            beta, rs, cs, rst, cst, thrp, Pva, PavT, g0);
        // yvin = v_fea + g_va @ a2
        mfma_nt<1, 128, 64, 2, 2, 1><<<dim3(DD / 64, TT / 128, g), blk, 0, stream>>>(
            Pva, nullptr, a2T + (long)g0 * DD * TT, nullptr,
            nullptr, yvin + (long)g0 * TT * DD, nullptr,
            v_fea + (long)g0 * TT * DD, rs + (long)g0 * TT, rst + (long)g0 * TT,
            nullptr, nullptr, TT, DD, TT, TT, TT,
            (long)TT * TT, (long)DD * TT, (long)TT * DD, 1.f, 0);
        // yain = a_fea + g_av @ v1
        mfma_nt<1, 128, 64, 2, 2, 1><<<dim3(DD / 64, TT / 128, g), blk, 0, stream>>>(
            PavT, nullptr, v1T + (long)g0 * DD * TT, nullptr,
            nullptr, yain + (long)g0 * TT * DD, nullptr,
            a_fea + (long)g0 * TT * DD, cs + (long)g0 * TT, cst + (long)g0 * TT,
            nullptr, nullptr, TT, DD, TT, TT, TT,
            (long)TT * TT, (long)DD * TT, (long)TT * DD, 1.f, 0);
    }

    // FC: y = relu(yin @ Wfc^T) fp32, then LN+fuse
    mfma_nt<1, 128, 64, 2, 2, 0><<<dim3(DD / 64, (unsigned)(MT / 128), 1), blk, 0, stream>>>(
        yvin, nullptr, Wvfcb, nullptr, yv, nullptr, nullptr, nullptr, nullptr,
        nullptr, nullptr, nullptr, (int)MT, DD, DD, DD, DD, 0, 0, 0, 1.f, 0);
    mfma_nt<1, 128, 64, 2, 2, 0><<<dim3(DD / 64, (unsigned)(MT / 128), 1), blk, 0, stream>>>(
        yain, nullptr, Wafcb, nullptr, ya, nullptr, nullptr, nullptr, nullptr,
        nullptr, nullptr, nullptr, (int)MT, DD, DD, DD, DD, 0, 0, 0, 1.f, 0);
    ln_fuse_kernel<<<dim3((unsigned)(MT / 4), 1, 1), blk, 0, stream>>>(
        yv, ya, lng, lnb, out_fuse, out_vpsp, out_apsp);
}

// Round 4
// 552.095 us; speedup vs baseline: 2.0036x; 1.0809x over previous
//
#include <hip/hip_runtime.h>
#include <math.h>

#define TT 2048
#define DD 256
#define NBATCH 8
#define EPSF 1e-8f

typedef unsigned short u16;
typedef __attribute__((ext_vector_type(8))) short short8;
typedef __attribute__((ext_vector_type(4))) float f32x4;

__device__ __forceinline__ u16 f2bf(float x) {
    unsigned int u = __builtin_bit_cast(unsigned int, x);
    u += 0x7fffu + ((u >> 16) & 1u);
    return (u16)(u >> 16);
}
__device__ __forceinline__ float bf2f(u16 h) {
    return __builtin_bit_cast(float, (unsigned int)h << 16);
}

// MFMA-fragment LDS index for a [rows x 32k] bf16 tile:
// elem(row,k) -> (((row>>4)*4+(k>>3))*16+(row&15))*8+(k&7)
// Fragment read for 16-row subtile t is ds_read_b128 at (t*64+lane)*8.
__device__ __forceinline__ int frag_dst(int row, int k) {
    return (((row >> 4) * 4 + (k >> 3)) * 16 + (row & 15)) * 8 + (k & 7);
}

template<int BR>
__device__ __forceinline__ void stage_tile(const u16* __restrict__ g, u16* s,
                                           int row0, int k0, int ldk, int tid)
{
    #pragma unroll
    for (int i = 0; i < BR / 64; ++i) {
        const int c = tid + 256 * i;
        const int row = c >> 2, q = c & 3;
        *(int4*)(s + frag_dst(row, q * 8)) =
            *(const int4*)(g + (long)(row0 + row) * ldk + k0 + q * 8);
    }
}

// ---------------------------------------------------------------------------
// Combined projections: z = 0:v2(split) 1:a1(split) 2:v1(bf16) 3:a2(bf16)
// 3-term split-bf16 MFMA (rel err ~3e-6). BM=BN=64, 2x2 waves.
// ---------------------------------------------------------------------------
__global__ __launch_bounds__(256)
void proj_kernel(const u16* __restrict__ vfh, const u16* __restrict__ vfl,
                 const u16* __restrict__ afh, const u16* __restrict__ afl,
                 const u16* __restrict__ Wsp,
                 u16* __restrict__ v2h, u16* __restrict__ v2l,
                 u16* __restrict__ a1h, u16* __restrict__ a1l,
                 u16* __restrict__ v1b, u16* __restrict__ a2b)
{
    const int zz = blockIdx.z;
    const u16* Ah = (zz == 1 || zz == 3) ? afh : vfh;
    const u16* Al = (zz == 1 || zz == 3) ? afl : vfl;
    const int widx = (zz == 0) ? 2 : (zz == 1) ? 4 : (zz == 2) ? 0 : 6;
    const u16* Bh = Wsp + widx * DD * DD;
    const u16* Bl = Bh + DD * DD;
    u16* Oh = (zz == 0) ? v2h : (zz == 1) ? a1h : (zz == 2) ? v1b : a2b;
    u16* Ol = (zz == 0) ? v2l : a1l;
    const bool split = zz < 2;

    __shared__ __align__(16) u16 Ah_s[64 * 32], Al_s[64 * 32];
    __shared__ __align__(16) u16 Bh_s[64 * 32], Bl_s[64 * 32];
    const int m0 = blockIdx.y * 64, n0 = blockIdx.x * 64;
    const int tid = threadIdx.x, lane = tid & 63, w = tid >> 6;
    const int wy = w >> 1, wx = w & 1;
    f32x4 acc[2][2] = {};

    for (int k0 = 0; k0 < DD; k0 += 32) {
        stage_tile<64>(Ah, Ah_s, m0, k0, DD, tid);
        stage_tile<64>(Al, Al_s, m0, k0, DD, tid);
        stage_tile<64>(Bh, Bh_s, n0, k0, DD, tid);
        stage_tile<64>(Bl, Bl_s, n0, k0, DD, tid);
        __syncthreads();
        short8 ah[2], al[2], bh[2], bl[2];
        #pragma unroll
        for (int i = 0; i < 2; ++i) {
            ah[i] = *(const short8*)(Ah_s + ((wy * 2 + i) * 64 + lane) * 8);
            al[i] = *(const short8*)(Al_s + ((wy * 2 + i) * 64 + lane) * 8);
        }
        #pragma unroll
        for (int j = 0; j < 2; ++j) {
            bh[j] = *(const short8*)(Bh_s + ((wx * 2 + j) * 64 + lane) * 8);
            bl[j] = *(const short8*)(Bl_s + ((wx * 2 + j) * 64 + lane) * 8);
        }
        #pragma unroll
        for (int i = 0; i < 2; ++i)
            #pragma unroll
            for (int j = 0; j < 2; ++j) {
                acc[i][j] = __builtin_amdgcn_mfma_f32_16x16x32_bf16(ah[i], bl[j], acc[i][j], 0, 0, 0);
                acc[i][j] = __builtin_amdgcn_mfma_f32_16x16x32_bf16(al[i], bh[j], acc[i][j], 0, 0, 0);
                acc[i][j] = __builtin_amdgcn_mfma_f32_16x16x32_bf16(ah[i], bh[j], acc[i][j], 0, 0, 0);
            }
        __syncthreads();
    }
    const int quad = lane >> 4, col = lane & 15;
    #pragma unroll
    for (int i = 0; i < 2; ++i)
        #pragma unroll
        for (int j = 0; j < 2; ++j) {
            const int c = n0 + (wx * 2 + j) * 16 + col;
            #pragma unroll
            for (int r = 0; r < 4; ++r) {
                const int row = m0 + (wy * 2 + i) * 16 + quad * 4 + r;
                float v = fmaxf(acc[i][j][r], 0.f);
                const u16 h = f2bf(v);
                Oh[(long)row * DD + c] = h;
                if (split) Ol[(long)row * DD + c] = f2bf(v - bf2f(h));
            }
        }
}

// ---------------------------------------------------------------------------
// Scores: beta(bf16) = relu(v2.a1/16), 3-term split MFMA; fused fp32 rs/cs
// atomics from the accumulators. BM=BN=128, 2x2 waves.
// ---------------------------------------------------------------------------
__global__ __launch_bounds__(256)
void score_kernel(const u16* __restrict__ v2h, const u16* __restrict__ v2l,
                  const u16* __restrict__ a1h, const u16* __restrict__ a1l,
                  u16* __restrict__ beta, float* __restrict__ rs, float* __restrict__ cs)
{
    __shared__ __align__(16) u16 Ah_s[128 * 32], Al_s[128 * 32];
    __shared__ __align__(16) u16 Bh_s[128 * 32], Bl_s[128 * 32];
    const int z = blockIdx.z;
    const int m0 = blockIdx.y * 128, n0 = blockIdx.x * 128;
    const int tid = threadIdx.x, lane = tid & 63, w = tid >> 6;
    const int wy = w >> 1, wx = w & 1;
    const long zoff = (long)z * TT * DD;
    f32x4 acc[4][4] = {};

    for (int k0 = 0; k0 < DD; k0 += 32) {
        stage_tile<128>(v2h + zoff, Ah_s, m0, k0, DD, tid);
        stage_tile<128>(v2l + zoff, Al_s, m0, k0, DD, tid);
        stage_tile<128>(a1h + zoff, Bh_s, n0, k0, DD, tid);
        stage_tile<128>(a1l + zoff, Bl_s, n0, k0, DD, tid);
        __syncthreads();
        short8 ah[4], al[4], bh[4], bl[4];
        #pragma unroll
        for (int i = 0; i < 4; ++i) {
            ah[i] = *(const short8*)(Ah_s + ((wy * 4 + i) * 64 + lane) * 8);
            al[i] = *(const short8*)(Al_s + ((wy * 4 + i) * 64 + lane) * 8);
        }
        #pragma unroll
        for (int j = 0; j < 4; ++j) {
            bh[j] = *(const short8*)(Bh_s + ((wx * 4 + j) * 64 + lane) * 8);
            bl[j] = *(const short8*)(Bl_s + ((wx * 4 + j) * 64 + lane) * 8);
        }
        #pragma unroll
        for (int i = 0; i < 4; ++i)
            #pragma unroll
            for (int j = 0; j < 4; ++j) {
                acc[i][j] = __builtin_amdgcn_mfma_f32_16x16x32_bf16(ah[i], bl[j], acc[i][j], 0, 0, 0);
                acc[i][j] = __builtin_amdgcn_mfma_f32_16x16x32_bf16(al[i], bh[j], acc[i][j], 0, 0, 0);
                acc[i][j] = __builtin_amdgcn_mfma_f32_16x16x32_bf16(ah[i], bh[j], acc[i][j], 0, 0, 0);
            }
        __syncthreads();
    }

    const int quad = lane >> 4, col = lane & 15;
    const float scale = 1.f / 16.f;
    #pragma unroll
    for (int i = 0; i < 4; ++i)
        #pragma unroll
        for (int j = 0; j < 4; ++j) {
            const int c = n0 + (wx * 4 + j) * 16 + col;
            #pragma unroll
            for (int r = 0; r < 4; ++r) {
                const int row = m0 + (wy * 4 + i) * 16 + quad * 4 + r;
                float v = fmaxf(acc[i][j][r] * scale, 0.f);
                acc[i][j][r] = v;
                beta[((long)z * TT + row) * TT + c] = f2bf(v);
            }
        }
    // row sums (fp32-exact)
    #pragma unroll
    for (int i = 0; i < 4; ++i)
        #pragma unroll
        for (int r = 0; r < 4; ++r) {
            float rp = 0.f;
            #pragma unroll
            for (int j = 0; j < 4; ++j) rp += acc[i][j][r];
            rp += __shfl_xor(rp, 1); rp += __shfl_xor(rp, 2);
            rp += __shfl_xor(rp, 4); rp += __shfl_xor(rp, 8);
            if (col == 0) {
                const int row = m0 + (wy * 4 + i) * 16 + quad * 4 + r;
                atomicAdd(&rs[(long)z * TT + row], rp);
            }
        }
    // col sums
    #pragma unroll
    for (int j = 0; j < 4; ++j) {
        float cp = 0.f;
        #pragma unroll
        for (int i = 0; i < 4; ++i)
            #pragma unroll
            for (int r = 0; r < 4; ++r) cp += acc[i][j][r];
        cp += __shfl_xor(cp, 16); cp += __shfl_xor(cp, 32);
        if (lane < 16) {
            const int c = n0 + (wx * 4 + j) * 16 + col;
            atomicAdd(&cs[(long)z * TT + c], cp);
        }
    }
}

// ---------------------------------------------------------------------------
// PV (v attends a): out = bf16( (thr-pass(beta_rows) @ a2) * inv + v_fea ).
// Threshold applied during A staging; rst accumulated in-loop (regs->LDS).
// BM=128 (t rows), BN=64 (d cols), K=TT.
// ---------------------------------------------------------------------------
__global__ __launch_bounds__(256)
void pv_va_kernel(const u16* __restrict__ beta, const u16* __restrict__ VT,
                  const float* __restrict__ rs, const float* __restrict__ thrp,
                  const float* __restrict__ resid, u16* __restrict__ outb)
{
    __shared__ __align__(16) u16 A_s[128 * 32], B_s[64 * 32];
    __shared__ float rthr[128], rsA[128], rowsum[128];
    const int z = blockIdx.z, m0 = blockIdx.y * 128, n0 = blockIdx.x * 64;
    const int tid = threadIdx.x, lane = tid & 63, w = tid >> 6;
    const int wy = w >> 1, wx = w & 1;
    const float thr = thrp[0] * 10.0f / (float)TT;
    if (tid < 128) {
        const float s = rs[(long)z * TT + m0 + tid];
        rsA[tid] = s; rthr[tid] = thr * (s + EPSF); rowsum[tid] = 0.f;
    }
    __syncthreads();
    f32x4 acc[4][2] = {};
    float rpart[2] = {0.f, 0.f};
    const int arow = tid >> 2, aq = tid & 3;

    for (int k0 = 0; k0 < TT; k0 += 32) {
        #pragma unroll
        for (int i = 0; i < 2; ++i) {
            const int row = arow + 64 * i;
            union { int4 v; u16 us[8]; } U;
            U.v = *(const int4*)(beta + ((long)z * TT + m0 + row) * TT + k0 + aq * 8);
            const float ct = rthr[row];
            float ss = 0.f;
            #pragma unroll
            for (int t = 0; t < 8; ++t) {
                const float v = bf2f(U.us[t]);
                if (v > ct) ss += v; else U.us[t] = 0;
            }
            *(int4*)(A_s + frag_dst(row, aq * 8)) = U.v;
            rpart[i] += ss;
        }
        stage_tile<64>(VT + (long)z * DD * TT, B_s, n0, k0, TT, tid);
        __syncthreads();
        short8 a[4], b[2];
        #pragma unroll
        for (int i = 0; i < 4; ++i)
            a[i] = *(const short8*)(A_s + ((wy * 4 + i) * 64 + lane) * 8);
        #pragma unroll
        for (int j = 0; j < 2; ++j)
            b[j] = *(const short8*)(B_s + ((wx * 2 + j) * 64 + lane) * 8);
        #pragma unroll
        for (int i = 0; i < 4; ++i)
            #pragma unroll
            for (int j = 0; j < 2; ++j)
                acc[i][j] = __builtin_amdgcn_mfma_f32_16x16x32_bf16(a[i], b[j], acc[i][j], 0, 0, 0);
        __syncthreads();
    }
    atomicAdd(&rowsum[arow], rpart[0]);
    atomicAdd(&rowsum[arow + 64], rpart[1]);
    __syncthreads();

    const int quad = lane >> 4, col = lane & 15;
    #pragma unroll
    for (int i = 0; i < 4; ++i)
        #pragma unroll
        for (int j = 0; j < 2; ++j) {
            const int c = n0 + (wx * 2 + j) * 16 + col;
            #pragma unroll
            for (int r = 0; r < 4; ++r) {
                const int lrow = (wy * 4 + i) * 16 + quad * 4 + r;
                const int row = m0 + lrow;
                const float inv = 1.0f / (rowsum[lrow] + EPSF * (rsA[lrow] + EPSF));
                const float v = acc[i][j][r] * inv + resid[((long)z * TT + row) * DD + c];
                outb[((long)z * TT + row) * DD + c] = f2bf(v);
            }
        }
}

// ---------------------------------------------------------------------------
// PV (a attends v): A(m,k) = beta[k][m] (transposed staging, col-threshold),
// cst accumulated per-thread (fixed m-set) then reduced once.
// ---------------------------------------------------------------------------
__global__ __launch_bounds__(256)
void pv_av_kernel(const u16* __restrict__ beta, const u16* __restrict__ VT,
                  const float* __restrict__ cs, const float* __restrict__ thrp,
                  const float* __restrict__ resid, u16* __restrict__ outb)
{
    __shared__ __align__(16) u16 A_s[128 * 32], B_s[64 * 32];
    __shared__ float cthr[128], csA[128], colsum[128];
    const int z = blockIdx.z, m0 = blockIdx.y * 128, n0 = blockIdx.x * 64;
    const int tid = threadIdx.x, lane = tid & 63, w = tid >> 6;
    const int wy = w >> 1, wx = w & 1;
    const float thr = thrp[0] * 10.0f / (float)TT;
    if (tid < 128) {
        const float s = cs[(long)z * TT + m0 + tid];
        csA[tid] = s; cthr[tid] = thr * (s + EPSF); colsum[tid] = 0.f;
    }
    __syncthreads();
    f32x4 acc[4][2] = {};
    const int aj = tid & 15;   // owns m = aj*8 .. aj*8+7 for the whole loop
    const int ak = tid >> 4;
    float cpart[8] = {0.f, 0.f, 0.f, 0.f, 0.f, 0.f, 0.f, 0.f};

    for (int k0 = 0; k0 < TT; k0 += 32) {
        #pragma unroll
        for (int i = 0; i < 2; ++i) {
            const int kk = ak + 16 * i;
            union { int4 v; u16 us[8]; } U;
            U.v = *(const int4*)(beta + ((long)z * TT + k0 + kk) * TT + m0 + aj * 8);
            #pragma unroll
            for (int t = 0; t < 8; ++t) {
                const int m = aj * 8 + t;
                const float v = bf2f(U.us[t]);
                u16 bits = 0;
                if (v > cthr[m]) { cpart[t] += v; bits = U.us[t]; }
                A_s[frag_dst(m, kk)] = bits;
            }
        }
        stage_tile<64>(VT + (long)z * DD * TT, B_s, n0, k0, TT, tid);
        __syncthreads();
        short8 a[4], b[2];
        #pragma unroll
        for (int i = 0; i < 4; ++i)
            a[i] = *(const short8*)(A_s + ((wy * 4 + i) * 64 + lane) * 8);
        #pragma unroll
        for (int j = 0; j < 2; ++j)
            b[j] = *(const short8*)(B_s + ((wx * 2 + j) * 64 + lane) * 8);
        #pragma unroll
        for (int i = 0; i < 4; ++i)
            #pragma unroll
            for (int j = 0; j < 2; ++j)
                acc[i][j] = __builtin_amdgcn_mfma_f32_16x16x32_bf16(a[i], b[j], acc[i][j], 0, 0, 0);
        __syncthreads();
    }
    #pragma unroll
    for (int t = 0; t < 8; ++t)
        atomicAdd(&colsum[aj * 8 + t], cpart[t]);
    __syncthreads();

    const int quad = lane >> 4, col = lane & 15;
    #pragma unroll
    for (int i = 0; i < 4; ++i)
        #pragma unroll
        for (int j = 0; j < 2; ++j) {
            const int c = n0 + (wx * 2 + j) * 16 + col;
            #pragma unroll
            for (int r = 0; r < 4; ++r) {
                const int lrow = (wy * 4 + i) * 16 + quad * 4 + r;
                const int row = m0 + lrow;
                const float inv = 1.0f / (colsum[lrow] + EPSF * (csA[lrow] + EPSF));
                const float v = acc[i][j][r] * inv + resid[((long)z * TT + row) * DD + c];
                outb[((long)z * TT + row) * DD + c] = f2bf(v);
            }
        }
}

// ---------------------------------------------------------------------------
// FC: y = relu(yin @ Wfc^T) fp32 out. z selects branch via fixed strides.
// ---------------------------------------------------------------------------
__global__ __launch_bounds__(256)
void fc_kernel(const u16* __restrict__ Ain, const u16* __restrict__ Wb,
               float* __restrict__ Cf)
{
    const int z = blockIdx.z;
    const u16* A = Ain + (size_t)z * (size_t)NBATCH * TT * DD;
    const u16* B = Wb + (size_t)z * DD * DD;
    float* C = Cf + (size_t)z * (size_t)NBATCH * TT * DD;
    __shared__ __align__(16) u16 A_s[128 * 32], B_s[64 * 32];
    const int m0 = blockIdx.y * 128, n0 = blockIdx.x * 64;
    const int tid = threadIdx.x, lane = tid & 63, w = tid >> 6;
    const int wy = w >> 1, wx = w & 1;
    f32x4 acc[4][2] = {};
    for (int k0 = 0; k0 < DD; k0 += 32) {
        stage_tile<128>(A, A_s, m0, k0, DD, tid);
        stage_tile<64>(B, B_s, n0, k0, DD, tid);
        __syncthreads();
        short8 a[4], b[2];
        #pragma unroll
        for (int i = 0; i < 4; ++i)
            a[i] = *(const short8*)(A_s + ((wy * 4 + i) * 64 + lane) * 8);
        #pragma unroll
        for (int j = 0; j < 2; ++j)
            b[j] = *(const short8*)(B_s + ((wx * 2 + j) * 64 + lane) * 8);
        #pragma unroll
        for (int i = 0; i < 4; ++i)
            #pragma unroll
            for (int j = 0; j < 2; ++j)
                acc[i][j] = __builtin_amdgcn_mfma_f32_16x16x32_bf16(a[i], b[j], acc[i][j], 0, 0, 0);
        __syncthreads();
    }
    const int quad = lane >> 4, col = lane & 15;
    #pragma unroll
    for (int i = 0; i < 4; ++i)
        #pragma unroll
        for (int j = 0; j < 2; ++j) {
            const int c = n0 + (wx * 2 + j) * 16 + col;
            #pragma unroll
            for (int r = 0; r < 4; ++r) {
                const int row = m0 + (wy * 4 + i) * 16 + quad * 4 + r;
                C[(long)row * DD + c] = fmaxf(acc[i][j][r], 0.f);
            }
        }
}

// ---------------------------------------------------------------------------
// Exact fp32 pred: recompute v2[0,t], a1[0,t] and their dot; compare.
// ---------------------------------------------------------------------------
__global__ __launch_bounds__(256)
void pred_exact(const float* __restrict__ vf, const float* __restrict__ af,
                const float* __restrict__ Wv2, const float* __restrict__ Wa1,
                const float* __restrict__ cs, const float* __restrict__ thrp,
                float* __restrict__ pred)
{
    __shared__ float vs[8][260];
    __shared__ float as_[8][260];
    __shared__ float red[4][8];
    const int t0 = blockIdx.x * 8;
    const int tid = threadIdx.x;
    {
        const int i = tid >> 5, c = (tid & 31) * 8;
        *(float4*)&vs[i][c] = *(const float4*)(vf + (long)(t0 + i) * DD + c);
        *(float4*)&vs[i][c + 4] = *(const float4*)(vf + (long)(t0 + i) * DD + c + 4);
        *(float4*)&as_[i][c] = *(const float4*)(af + (long)(t0 + i) * DD + c);
        *(float4*)&as_[i][c + 4] = *(const float4*)(af + (long)(t0 + i) * DD + c + 4);
    }
    __syncthreads();
    const int j = tid;
    float av[8] = {0.f}, aa[8] = {0.f};
    for (int k = 0; k < DD; k += 4) {
        const float4 wv = *(const float4*)(Wv2 + (long)j * DD + k);
        const float4 wa = *(const float4*)(Wa1 + (long)j * DD + k);
        #pragma unroll
        for (int i = 0; i < 8; ++i) {
            const float4 x = *(const float4*)&vs[i][k];
            av[i] += wv.x * x.x + wv.y * x.y + wv.z * x.z + wv.w * x.w;
            const float4 y = *(const float4*)&as_[i][k];
            aa[i] += wa.x * y.x + wa.y * y.y + wa.z * y.z + wa.w * y.w;
        }
    }
    float p[8];
    #pragma unroll
    for (int i = 0; i < 8; ++i)
        p[i] = fmaxf(av[i], 0.f) * fmaxf(aa[i], 0.f);
    #pragma unroll
    for (int off = 32; off > 0; off >>= 1)
        #pragma unroll
        for (int i = 0; i < 8; ++i) p[i] += __shfl_xor(p[i], off);
    const int lane = tid & 63, wv_ = tid >> 6;
    if (lane == 0)
        #pragma unroll
        for (int i = 0; i < 8; ++i) red[wv_][i] = p[i];
    __syncthreads();
    if (tid < 8) {
        float d = red[0][tid] + red[1][tid] + red[2][tid] + red[3][tid];
        d = fmaxf(d * (1.f / 16.f), 0.f);
        const float thr = thrp[0] * 10.0f / (float)TT;
        pred[t0 + tid] = (d > thr * (cs[t0 + tid] + EPSF)) ? 1.0f : 0.0f;
    }
}

// ---------------------------------------------------------------------------
// Batch transpose bf16: [8][2048][256] -> [8][256][2048]; z<8: v1, z>=8: a2.
// ---------------------------------------------------------------------------
__global__ __launch_bounds__(256)
void transpose2(const u16* __restrict__ v1b, u16* __restrict__ v1T,
                const u16* __restrict__ a2b, u16* __restrict__ a2T)
{
    __shared__ u16 sm[64][72];
    const int zz = blockIdx.z;
    const u16* src = (zz < 8) ? v1b : a2b;
    u16* dst = (zz < 8) ? v1T : a2T;
    const int b = zz & 7;
    const int t0 = blockIdx.y * 64, d0 = blockIdx.x * 64;
    const int tid = threadIdx.x;
    {
        const int r = tid >> 2, c16 = (tid & 3) * 16;
        const u16* s = src + ((long)b * TT + t0 + r) * DD + d0 + c16;
        *(int4*)&sm[r][c16] = *(const int4*)s;
        *(int4*)&sm[r][c16 + 8] = *(const int4*)(s + 8);
    }
    __syncthreads();
    {
        const int d = tid >> 2, r16 = (tid & 3) * 16;
        unsigned pk[8];
        #pragma unroll
        for (int q = 0; q < 8; ++q)
            pk[q] = (unsigned)sm[r16 + 2 * q][d] | ((unsigned)sm[r16 + 2 * q + 1][d] << 16);
        u16* o = dst + ((long)b * DD + d0 + d) * TT + t0 + r16;
        *(int4*)o = int4{(int)pk[0], (int)pk[1], (int)pk[2], (int)pk[3]};
        *(int4*)(o + 8) = int4{(int)pk[4], (int)pk[5], (int)pk[6], (int)pk[7]};
    }
}

// ---------------------------------------------------------------------------
// Split v_fea/a_fea fp32 -> bf16 h/l pairs. grid.y: 0=v, 1=a.
// ---------------------------------------------------------------------------
__global__ __launch_bounds__(256)
void split_feat(const float* __restrict__ vf, const float* __restrict__ af,
                u16* __restrict__ vfh, u16* __restrict__ vfl,
                u16* __restrict__ afh, u16* __restrict__ afl)
{
    const long i4 = ((long)blockIdx.x * 256 + threadIdx.x) * 4;
    const float* src = blockIdx.y ? af : vf;
    u16* dh = blockIdx.y ? afh : vfh;
    u16* dl = blockIdx.y ? afl : vfl;
    float4 a = *(const float4*)(src + i4);
    ushort4 h4, l4; u16 h;
    h = f2bf(a.x); h4.x = h; l4.x = f2bf(a.x - bf2f(h));
    h = f2bf(a.y); h4.y = h; l4.y = f2bf(a.y - bf2f(h));
    h = f2bf(a.z); h4.z = h; l4.z = f2bf(a.z - bf2f(h));
    h = f2bf(a.w); h4.w = h; l4.w = f2bf(a.w - bf2f(h));
    *(ushort4*)(dh + i4) = h4;
    *(ushort4*)(dl + i4) = l4;
}

// ---------------------------------------------------------------------------
// Split/convert 6 weight matrices into Wsp: [Wv1h Wv1l Wv2h Wv2l Wa1h Wa1l
// Wa2h Wa2l Wvfcb Wafcb], each DD*DD. grid.y = task 0..5.
// ---------------------------------------------------------------------------
__global__ __launch_bounds__(256)
void split_w(const float* __restrict__ w0, const float* __restrict__ w1,
             const float* __restrict__ w2, const float* __restrict__ w3,
             const float* __restrict__ w4, const float* __restrict__ w5,
             u16* __restrict__ out)
{
    const int t = blockIdx.y;
    const float* w = (t == 0) ? w0 : (t == 1) ? w1 : (t == 2) ? w2
                   : (t == 3) ? w3 : (t == 4) ? w4 : w5;
    const int i4 = (blockIdx.x * 256 + threadIdx.x) * 4;
    float4 a = *(const float4*)(w + i4);
    if (t < 4) {
        u16* oh = out + (size_t)t * 2 * DD * DD;
        u16* ol = oh + DD * DD;
        ushort4 h4, l4; u16 h;
        h = f2bf(a.x); h4.x = h; l4.x = f2bf(a.x - bf2f(h));
        h = f2bf(a.y); h4.y = h; l4.y = f2bf(a.y - bf2f(h));
        h = f2bf(a.z); h4.z = h; l4.z = f2bf(a.z - bf2f(h));
        h = f2bf(a.w); h4.w = h; l4.w = f2bf(a.w - bf2f(h));
        *(ushort4*)(oh + i4) = h4;
        *(ushort4*)(ol + i4) = l4;
    } else {
        u16* ob = out + (size_t)8 * DD * DD + (size_t)(t - 4) * DD * DD;
        ushort4 o;
        o.x = f2bf(a.x); o.y = f2bf(a.y); o.z = f2bf(a.z); o.w = f2bf(a.w);
        *(ushort4*)(ob + i4) = o;
    }
}

// ---------------------------------------------------------------------------
// LayerNorm both branches + fuse. 4 rows/block, 1 wave per row. fp32 in/out.
// ---------------------------------------------------------------------------
__global__ __launch_bounds__(256)
void ln_fuse_kernel(const float* __restrict__ yv, const float* __restrict__ ya,
                    const float* __restrict__ g, const float* __restrict__ b,
                    float* __restrict__ fuse, float* __restrict__ vpsp,
                    float* __restrict__ apsp)
{
    const long row = (long)blockIdx.x * 4 + (threadIdx.x >> 6);
    const int lane = threadIdx.x & 63;
    const float4 xv = *(const float4*)(yv + row * DD + lane * 4);
    const float4 xa = *(const float4*)(ya + row * DD + lane * 4);
    float sv = xv.x + xv.y + xv.z + xv.w;
    float sa = xa.x + xa.y + xa.z + xa.w;
    #pragma unroll
    for (int off = 32; off > 0; off >>= 1) {
        sv += __shfl_xor(sv, off);
        sa += __shfl_xor(sa, off);
    }
    const float mv = sv * (1.f / 256.f);
    const float ma = sa * (1.f / 256.f);
    const float dv0 = xv.x - mv, dv1 = xv.y - mv, dv2 = xv.z - mv, dv3 = xv.w - mv;
    const float da0 = xa.x - ma, da1 = xa.y - ma, da2 = xa.z - ma, da3 = xa.w - ma;
    float qv = dv0 * dv0 + dv1 * dv1 + dv2 * dv2 + dv3 * dv3;
    float qa = da0 * da0 + da1 * da1 + da2 * da2 + da3 * da3;
    #pragma unroll
    for (int off = 32; off > 0; off >>= 1) {
        qv += __shfl_xor(qv, off);
        qa += __shfl_xor(qa, off);
    }
    const float rv = rsqrtf(qv * (1.f / 256.f) + 1e-6f);
    const float ra = rsqrtf(qa * (1.f / 256.f) + 1e-6f);
    const float4 gg = *(const float4*)(g + lane * 4);
    const float4 bb = *(const float4*)(b + lane * 4);
    float4 ov, oa, of;
    ov.x = dv0 * rv * gg.x + bb.x; ov.y = dv1 * rv * gg.y + bb.y;
    ov.z = dv2 * rv * gg.z + bb.z; ov.w = dv3 * rv * gg.w + bb.w;
    oa.x = da0 * ra * gg.x + bb.x; oa.y = da1 * ra * gg.y + bb.y;
    oa.z = da2 * ra * gg.z + bb.z; oa.w = da3 * ra * gg.w + bb.w;
    of.x = 0.5f * (ov.x + oa.x); of.y = 0.5f * (ov.y + oa.y);
    of.z = 0.5f * (ov.z + oa.z); of.w = 0.5f * (ov.w + oa.w);
    *(float4*)(vpsp + row * DD + lane * 4) = ov;
    *(float4*)(apsp + row * DD + lane * 4) = oa;
    *(float4*)(fuse + row * DD + lane * 4) = of;
}

extern "C" void kernel_launch(void* const* d_in, const int* in_sizes, int n_in,
                              void* d_out, int out_size, void* d_ws, size_t ws_size,
                              hipStream_t stream)
{
    const float* a_fea = (const float*)d_in[0];
    const float* v_fea = (const float*)d_in[1];
    const float* thrp  = (const float*)d_in[2];
    const float* Wv1   = (const float*)d_in[3];
    const float* Wv2   = (const float*)d_in[4];
    const float* Wvfc  = (const float*)d_in[5];
    const float* Wa1   = (const float*)d_in[6];
    const float* Wa2   = (const float*)d_in[7];
    const float* Wafc  = (const float*)d_in[8];
    const float* lng   = (const float*)d_in[9];
    const float* lnb   = (const float*)d_in[10];

    const long MT = (long)NBATCH * TT;
    float* out_fuse = (float*)d_out;
    float* out_vpsp = out_fuse + MT * DD;
    float* out_apsp = out_vpsp + MT * DD;
    float* out_pred = out_apsp + MT * DD;

    // ws: v2h v2l a1h a1l v1b a2b v1T a2T (8xfb) | rs cs | Wsp(10xDDDD) |
    //     beta(bf16, 67MB; transient vfh/vfl/afh/afl alias its front)
    // aliases: yv(f32) over v2h+v2l, ya over a1h+a1l, yvin=v1b, yain=a2b
    char* ws = (char*)d_ws;
    const size_t fb = (size_t)MT * DD * sizeof(u16);
    const size_t sumB = (size_t)MT * sizeof(float);
    u16* v2h = (u16*)(ws + 0 * fb);
    u16* v2l = (u16*)(ws + 1 * fb);
    u16* a1h = (u16*)(ws + 2 * fb);
    u16* a1l = (u16*)(ws + 3 * fb);
    u16* v1b = (u16*)(ws + 4 * fb);
    u16* a2b = (u16*)(ws + 5 * fb);
    u16* v1T = (u16*)(ws + 6 * fb);
    u16* a2T = (u16*)(ws + 7 * fb);
    char* p = ws + 8 * fb;
    float* rs = (float*)(p + 0 * sumB);
    float* cs = (float*)(p + 1 * sumB);
    u16* Wsp  = (u16*)(p + 2 * sumB);
    char* q = p + 2 * sumB + 10 * DD * DD * sizeof(u16);
    u16* beta = (u16*)q;                       // 8 * TT*TT bf16
    u16* vfh = (u16*)q;                        // transient, dead before score
    u16* vfl = vfh + MT * DD;
    u16* afh = vfl + MT * DD;
    u16* afl = afh + MT * DD;
    float* yv = (float*)(ws + 0 * fb);
    float* ya = (float*)(ws + 2 * fb);
    u16* yvin = v1b;
    u16* yain = a2b;

    hipMemsetAsync(rs, 0, 2 * sumB, stream);

    const dim3 blk(256, 1, 1);

    split_feat<<<dim3((unsigned)(MT * DD / 1024), 2, 1), blk, 0, stream>>>(
        v_fea, a_fea, vfh, vfl, afh, afl);
    split_w<<<dim3(DD * DD / 1024, 6, 1), blk, 0, stream>>>(
        Wv1, Wv2, Wa1, Wa2, Wvfc, Wafc, Wsp);

    proj_kernel<<<dim3(DD / 64, (unsigned)(MT / 64), 4), blk, 0, stream>>>(
        vfh, vfl, afh, afl, Wsp, v2h, v2l, a1h, a1l, v1b, a2b);
    transpose2<<<dim3(DD / 64, TT / 64, 16), blk, 0, stream>>>(v1b, v1T, a2b, a2T);

    score_kernel<<<dim3(TT / 128, TT / 128, NBATCH), blk, 0, stream>>>(
        v2h, v2l, a1h, a1l, beta, rs, cs);
    pred_exact<<<dim3(TT / 8, 1, 1), blk, 0, stream>>>(
        v_fea, a_fea, Wv2, Wa1, cs, thrp, out_pred);

    pv_va_kernel<<<dim3(DD / 64, TT / 128, NBATCH), blk, 0, stream>>>(
        beta, a2T, rs, thrp, v_fea, yvin);
    pv_av_kernel<<<dim3(DD / 64, TT / 128, NBATCH), blk, 0, stream>>>(
        beta, v1T, cs, thrp, a_fea, yain);

    fc_kernel<<<dim3(DD / 64, (unsigned)(MT / 128), 2), blk, 0, stream>>>(
        yvin, Wsp + 8 * DD * DD, yv);
    ln_fuse_kernel<<<dim3((unsigned)(MT / 4), 1, 1), blk, 0, stream>>>(
        yv, ya, lng, lnb, out_fuse, out_vpsp, out_apsp);
}

// Round 5
// 446.353 us; speedup vs baseline: 2.4783x; 1.2369x over previous
//
#include <hip/hip_runtime.h>
#include <math.h>

#define TT 2048
#define DD 256
#define NBATCH 8
#define EPSF 1e-8f

typedef unsigned short u16;
typedef __attribute__((ext_vector_type(8))) short short8;
typedef __attribute__((ext_vector_type(4))) float f32x4;

__device__ __forceinline__ u16 f2bf(float x) {
    unsigned int u = __builtin_bit_cast(unsigned int, x);
    u += 0x7fffu + ((u >> 16) & 1u);
    return (u16)(u >> 16);
}
__device__ __forceinline__ float bf2f(u16 h) {
    return __builtin_bit_cast(float, (unsigned int)h << 16);
}

// MFMA-fragment LDS index for a [rows x 32k] bf16 tile:
// elem(row,k) -> (((row>>4)*4+(k>>3))*16+(row&15))*8+(k&7)
// b128 stores/loads on this layout spread uniformly over all 32 banks.
__device__ __forceinline__ int frag_dst(int row, int k) {
    return (((row >> 4) * 4 + (k >> 3)) * 16 + (row & 15)) * 8 + (k & 7);
}

template<int BR>
__device__ __forceinline__ void stage_tile(const u16* __restrict__ g, u16* s,
                                           int row0, int k0, int ldk, int tid)
{
    #pragma unroll
    for (int i = 0; i < BR / 64; ++i) {
        const int c = tid + 256 * i;
        const int row = c >> 2, q = c & 3;
        *(int4*)(s + frag_dst(row, q * 8)) =
            *(const int4*)(g + (long)(row0 + row) * ldk + k0 + q * 8);
    }
}

// ---------------------------------------------------------------------------
// Combined projections. z = 0:v2(split h/l) 1:a1(split h/l)
//                        2:v1 -> v1T (register-transposed bf16)
//                        3:a2 -> a2T
// 3-term split-bf16 MFMA (rel err ~3e-6). BM=BN=64, 2x2 waves.
// ---------------------------------------------------------------------------
__global__ __launch_bounds__(256)
void proj_kernel(const u16* __restrict__ vfh, const u16* __restrict__ vfl,
                 const u16* __restrict__ afh, const u16* __restrict__ afl,
                 const u16* __restrict__ Wsp,
                 u16* __restrict__ v2h, u16* __restrict__ v2l,
                 u16* __restrict__ a1h, u16* __restrict__ a1l,
                 u16* __restrict__ v1T, u16* __restrict__ a2T)
{
    const int zz = blockIdx.z;
    const u16* Ah = (zz == 1 || zz == 3) ? afh : vfh;
    const u16* Al = (zz == 1 || zz == 3) ? afl : vfl;
    const int widx = (zz == 0) ? 2 : (zz == 1) ? 4 : (zz == 2) ? 0 : 6;
    const u16* Bh = Wsp + widx * DD * DD;
    const u16* Bl = Bh + DD * DD;
    const bool split = zz < 2;
    u16* Oh = (zz == 0) ? v2h : a1h;
    u16* Ol = (zz == 0) ? v2l : a1l;
    u16* OT = (zz == 2) ? v1T : a2T;

    __shared__ __align__(16) u16 Ah_s[64 * 32], Al_s[64 * 32];
    __shared__ __align__(16) u16 Bh_s[64 * 32], Bl_s[64 * 32];
    const int m0 = blockIdx.y * 64, n0 = blockIdx.x * 64;
    const int tid = threadIdx.x, lane = tid & 63, w = tid >> 6;
    const int wy = w >> 1, wx = w & 1;
    f32x4 acc[2][2] = {};

    for (int k0 = 0; k0 < DD; k0 += 32) {
        stage_tile<64>(Ah, Ah_s, m0, k0, DD, tid);
        stage_tile<64>(Al, Al_s, m0, k0, DD, tid);
        stage_tile<64>(Bh, Bh_s, n0, k0, DD, tid);
        stage_tile<64>(Bl, Bl_s, n0, k0, DD, tid);
        __syncthreads();
        short8 ah[2], al[2], bh[2], bl[2];
        #pragma unroll
        for (int i = 0; i < 2; ++i) {
            ah[i] = *(const short8*)(Ah_s + ((wy * 2 + i) * 64 + lane) * 8);
            al[i] = *(const short8*)(Al_s + ((wy * 2 + i) * 64 + lane) * 8);
        }
        #pragma unroll
        for (int j = 0; j < 2; ++j) {
            bh[j] = *(const short8*)(Bh_s + ((wx * 2 + j) * 64 + lane) * 8);
            bl[j] = *(const short8*)(Bl_s + ((wx * 2 + j) * 64 + lane) * 8);
        }
        #pragma unroll
        for (int i = 0; i < 2; ++i)
            #pragma unroll
            for (int j = 0; j < 2; ++j) {
                acc[i][j] = __builtin_amdgcn_mfma_f32_16x16x32_bf16(ah[i], bl[j], acc[i][j], 0, 0, 0);
                acc[i][j] = __builtin_amdgcn_mfma_f32_16x16x32_bf16(al[i], bh[j], acc[i][j], 0, 0, 0);
                acc[i][j] = __builtin_amdgcn_mfma_f32_16x16x32_bf16(ah[i], bh[j], acc[i][j], 0, 0, 0);
            }
        __syncthreads();
    }
    const int quad = lane >> 4, col = lane & 15;
    #pragma unroll
    for (int i = 0; i < 2; ++i)
        #pragma unroll
        for (int j = 0; j < 2; ++j) {
            const int c = n0 + (wx * 2 + j) * 16 + col;
            const int rbase = m0 + (wy * 2 + i) * 16 + quad * 4;
            if (split) {
                #pragma unroll
                for (int r = 0; r < 4; ++r) {
                    const float v = fmaxf(acc[i][j][r], 0.f);
                    const u16 h = f2bf(v);
                    Oh[(long)(rbase + r) * DD + c] = h;
                    Ol[(long)(rbase + r) * DD + c] = f2bf(v - bf2f(h));
                }
            } else {
                // transposed: OT[b][d=c][t]; 4 consecutive t = one b64 store
                short4 pk;
                pk.x = (short)f2bf(fmaxf(acc[i][j][0], 0.f));
                pk.y = (short)f2bf(fmaxf(acc[i][j][1], 0.f));
                pk.z = (short)f2bf(fmaxf(acc[i][j][2], 0.f));
                pk.w = (short)f2bf(fmaxf(acc[i][j][3], 0.f));
                const int b = rbase >> 11, t = rbase & (TT - 1);
                *(short4*)(OT + ((long)b * DD + c) * TT + t) = pk;
            }
        }
}

// ---------------------------------------------------------------------------
// Scores: beta(bf16) = relu(v2.a1/16), 3-term split MFMA.
// Also emits betaT (register-transposed, b64 stores) and fp32-exact rs/cs.
// BM=BN=128, 2x2 waves.
// ---------------------------------------------------------------------------
__global__ __launch_bounds__(256)
void score_kernel(const u16* __restrict__ v2h, const u16* __restrict__ v2l,
                  const u16* __restrict__ a1h, const u16* __restrict__ a1l,
                  u16* __restrict__ beta, u16* __restrict__ betaT,
                  float* __restrict__ rs, float* __restrict__ cs)
{
    __shared__ __align__(16) u16 Ah_s[128 * 32], Al_s[128 * 32];
    __shared__ __align__(16) u16 Bh_s[128 * 32], Bl_s[128 * 32];
    const int z = blockIdx.z;
    const int m0 = blockIdx.y * 128, n0 = blockIdx.x * 128;
    const int tid = threadIdx.x, lane = tid & 63, w = tid >> 6;
    const int wy = w >> 1, wx = w & 1;
    const long zoff = (long)z * TT * DD;
    f32x4 acc[4][4] = {};

    for (int k0 = 0; k0 < DD; k0 += 32) {
        stage_tile<128>(v2h + zoff, Ah_s, m0, k0, DD, tid);
        stage_tile<128>(v2l + zoff, Al_s, m0, k0, DD, tid);
        stage_tile<128>(a1h + zoff, Bh_s, n0, k0, DD, tid);
        stage_tile<128>(a1l + zoff, Bl_s, n0, k0, DD, tid);
        __syncthreads();
        short8 ah[4], al[4], bh[4], bl[4];
        #pragma unroll
        for (int i = 0; i < 4; ++i) {
            ah[i] = *(const short8*)(Ah_s + ((wy * 4 + i) * 64 + lane) * 8);
            al[i] = *(const short8*)(Al_s + ((wy * 4 + i) * 64 + lane) * 8);
        }
        #pragma unroll
        for (int j = 0; j < 4; ++j) {
            bh[j] = *(const short8*)(Bh_s + ((wx * 4 + j) * 64 + lane) * 8);
            bl[j] = *(const short8*)(Bl_s + ((wx * 4 + j) * 64 + lane) * 8);
        }
        #pragma unroll
        for (int i = 0; i < 4; ++i)
            #pragma unroll
            for (int j = 0; j < 4; ++j) {
                acc[i][j] = __builtin_amdgcn_mfma_f32_16x16x32_bf16(ah[i], bl[j], acc[i][j], 0, 0, 0);
                acc[i][j] = __builtin_amdgcn_mfma_f32_16x16x32_bf16(al[i], bh[j], acc[i][j], 0, 0, 0);
                acc[i][j] = __builtin_amdgcn_mfma_f32_16x16x32_bf16(ah[i], bh[j], acc[i][j], 0, 0, 0);
            }
        __syncthreads();
    }

    const int quad = lane >> 4, col = lane & 15;
    const float scale = 1.f / 16.f;
    #pragma unroll
    for (int i = 0; i < 4; ++i)
        #pragma unroll
        for (int j = 0; j < 4; ++j) {
            const int c = n0 + (wx * 4 + j) * 16 + col;
            const int rbase = m0 + (wy * 4 + i) * 16 + quad * 4;
            short4 pk;
            #pragma unroll
            for (int r = 0; r < 4; ++r) {
                float v = fmaxf(acc[i][j][r] * scale, 0.f);
                acc[i][j][r] = v;
                const u16 h = f2bf(v);
                ((u16*)&pk)[r] = h;
                beta[((long)z * TT + rbase + r) * TT + c] = h;
            }
            *(short4*)(betaT + ((long)z * TT + c) * TT + rbase) = pk;
        }
    // row sums (fp32-exact)
    #pragma unroll
    for (int i = 0; i < 4; ++i)
        #pragma unroll
        for (int r = 0; r < 4; ++r) {
            float rp = 0.f;
            #pragma unroll
            for (int j = 0; j < 4; ++j) rp += acc[i][j][r];
            rp += __shfl_xor(rp, 1); rp += __shfl_xor(rp, 2);
            rp += __shfl_xor(rp, 4); rp += __shfl_xor(rp, 8);
            if (col == 0) {
                const int row = m0 + (wy * 4 + i) * 16 + quad * 4 + r;
                atomicAdd(&rs[(long)z * TT + row], rp);
            }
        }
    // col sums
    #pragma unroll
    for (int j = 0; j < 4; ++j) {
        float cp = 0.f;
        #pragma unroll
        for (int i = 0; i < 4; ++i)
            #pragma unroll
            for (int r = 0; r < 4; ++r) cp += acc[i][j][r];
        cp += __shfl_xor(cp, 16); cp += __shfl_xor(cp, 32);
        if (lane < 16) {
            const int c = n0 + (wx * 4 + j) * 16 + col;
            atomicAdd(&cs[(long)z * TT + c], cp);
        }
    }
}

// ---------------------------------------------------------------------------
// Unified PV. z<8: v-attends-a (P=beta rows, sums=rs, V=a2T, resid=v_fea)
//             z>=8: a-attends-v (P=betaT rows, sums=cs, V=v1T, resid=a_fea)
// Threshold applied during row staging (vectorized b128 LDS writes, uniform
// bank spread); thresholded row sums accumulated in-loop; epilogue renorms,
// adds residual, emits bf16. BM=128, BN=64, K=TT.
// ---------------------------------------------------------------------------
__global__ __launch_bounds__(256)
void pv_kernel(const u16* __restrict__ beta, const u16* __restrict__ betaT,
               const u16* __restrict__ a2T, const u16* __restrict__ v1T,
               const float* __restrict__ rs, const float* __restrict__ cs,
               const float* __restrict__ thrp,
               const float* __restrict__ v_fea, const float* __restrict__ a_fea,
               u16* __restrict__ yvin, u16* __restrict__ yain)
{
    __shared__ __align__(16) u16 A_s[128 * 32], B_s[64 * 32];
    __shared__ float sthr[128], sA[128], ssum[128];
    const int zz = blockIdx.z;
    const int z = zz & 7;
    const bool av = zz >= 8;
    const u16* P      = av ? betaT : beta;
    const u16* VT     = av ? v1T : a2T;
    const float* sums = av ? cs : rs;
    const float* resid = av ? a_fea : v_fea;
    u16* outb         = av ? yain : yvin;

    const int m0 = blockIdx.y * 128, n0 = blockIdx.x * 64;
    const int tid = threadIdx.x, lane = tid & 63, w = tid >> 6;
    const int wy = w >> 1, wx = w & 1;
    const float thr = thrp[0] * 10.0f / (float)TT;
    if (tid < 128) {
        const float s = sums[(long)z * TT + m0 + tid];
        sA[tid] = s; sthr[tid] = thr * (s + EPSF); ssum[tid] = 0.f;
    }
    __syncthreads();
    f32x4 acc[4][2] = {};
    float rpart[2] = {0.f, 0.f};
    const int arow = tid >> 2, aq = tid & 3;

    for (int k0 = 0; k0 < TT; k0 += 32) {
        #pragma unroll
        for (int i = 0; i < 2; ++i) {
            const int row = arow + 64 * i;
            union { int4 v; u16 us[8]; } U;
            U.v = *(const int4*)(P + ((long)z * TT + m0 + row) * TT + k0 + aq * 8);
            const float ct = sthr[row];
            float ss = 0.f;
            #pragma unroll
            for (int t = 0; t < 8; ++t) {
                const float v = bf2f(U.us[t]);
                if (v > ct) ss += v; else U.us[t] = 0;
            }
            *(int4*)(A_s + frag_dst(row, aq * 8)) = U.v;
            rpart[i] += ss;
        }
        stage_tile<64>(VT + (long)z * DD * TT, B_s, n0, k0, TT, tid);
        __syncthreads();
        short8 a[4], b[2];
        #pragma unroll
        for (int i = 0; i < 4; ++i)
            a[i] = *(const short8*)(A_s + ((wy * 4 + i) * 64 + lane) * 8);
        #pragma unroll
        for (int j = 0; j < 2; ++j)
            b[j] = *(const short8*)(B_s + ((wx * 2 + j) * 64 + lane) * 8);
        #pragma unroll
        for (int i = 0; i < 4; ++i)
            #pragma unroll
            for (int j = 0; j < 2; ++j)
                acc[i][j] = __builtin_amdgcn_mfma_f32_16x16x32_bf16(a[i], b[j], acc[i][j], 0, 0, 0);
        __syncthreads();
    }
    atomicAdd(&ssum[arow], rpart[0]);
    atomicAdd(&ssum[arow + 64], rpart[1]);
    __syncthreads();

    const int quad = lane >> 4, col = lane & 15;
    #pragma unroll
    for (int i = 0; i < 4; ++i)
        #pragma unroll
        for (int j = 0; j < 2; ++j) {
            const int c = n0 + (wx * 2 + j) * 16 + col;
            #pragma unroll
            for (int r = 0; r < 4; ++r) {
                const int lrow = (wy * 4 + i) * 16 + quad * 4 + r;
                const int row = m0 + lrow;
                const float inv = 1.0f / (ssum[lrow] + EPSF * (sA[lrow] + EPSF));
                const float v = acc[i][j][r] * inv + resid[((long)z * TT + row) * DD + c];
                outb[((long)z * TT + row) * DD + c] = f2bf(v);
            }
        }
}

// ---------------------------------------------------------------------------
// FC: y = relu(yin @ Wfc^T) fp32 out. z selects branch via fixed strides.
// ---------------------------------------------------------------------------
__global__ __launch_bounds__(256)
void fc_kernel(const u16* __restrict__ Ain, const u16* __restrict__ Wb,
               float* __restrict__ Cf)
{
    const int z = blockIdx.z;
    const u16* A = Ain + (size_t)z * (size_t)NBATCH * TT * DD;
    const u16* B = Wb + (size_t)z * DD * DD;
    float* C = Cf + (size_t)z * (size_t)NBATCH * TT * DD;
    __shared__ __align__(16) u16 A_s[128 * 32], B_s[64 * 32];
    const int m0 = blockIdx.y * 128, n0 = blockIdx.x * 64;
    const int tid = threadIdx.x, lane = tid & 63, w = tid >> 6;
    const int wy = w >> 1, wx = w & 1;
    f32x4 acc[4][2] = {};
    for (int k0 = 0; k0 < DD; k0 += 32) {
        stage_tile<128>(A, A_s, m0, k0, DD, tid);
        stage_tile<64>(B, B_s, n0, k0, DD, tid);
        __syncthreads();
        short8 a[4], b[2];
        #pragma unroll
        for (int i = 0; i < 4; ++i)
            a[i] = *(const short8*)(A_s + ((wy * 4 + i) * 64 + lane) * 8);
        #pragma unroll
        for (int j = 0; j < 2; ++j)
            b[j] = *(const short8*)(B_s + ((wx * 2 + j) * 64 + lane) * 8);
        #pragma unroll
        for (int i = 0; i < 4; ++i)
            #pragma unroll
            for (int j = 0; j < 2; ++j)
                acc[i][j] = __builtin_amdgcn_mfma_f32_16x16x32_bf16(a[i], b[j], acc[i][j], 0, 0, 0);
        __syncthreads();
    }
    const int quad = lane >> 4, col = lane & 15;
    #pragma unroll
    for (int i = 0; i < 4; ++i)
        #pragma unroll
        for (int j = 0; j < 2; ++j) {
            const int c = n0 + (wx * 2 + j) * 16 + col;
            #pragma unroll
            for (int r = 0; r < 4; ++r) {
                const int row = m0 + (wy * 4 + i) * 16 + quad * 4 + r;
                C[(long)row * DD + c] = fmaxf(acc[i][j][r], 0.f);
            }
        }
}

// ---------------------------------------------------------------------------
// Exact fp32 pred: recompute v2[0,t], a1[0,t] and their dot; compare.
// ---------------------------------------------------------------------------
__global__ __launch_bounds__(256)
void pred_exact(const float* __restrict__ vf, const float* __restrict__ af,
                const float* __restrict__ Wv2, const float* __restrict__ Wa1,
                const float* __restrict__ cs, const float* __restrict__ thrp,
                float* __restrict__ pred)
{
    __shared__ float vs[8][260];
    __shared__ float as_[8][260];
    __shared__ float red[4][8];
    const int t0 = blockIdx.x * 8;
    const int tid = threadIdx.x;
    {
        const int i = tid >> 5, c = (tid & 31) * 8;
        *(float4*)&vs[i][c] = *(const float4*)(vf + (long)(t0 + i) * DD + c);
        *(float4*)&vs[i][c + 4] = *(const float4*)(vf + (long)(t0 + i) * DD + c + 4);
        *(float4*)&as_[i][c] = *(const float4*)(af + (long)(t0 + i) * DD + c);
        *(float4*)&as_[i][c + 4] = *(const float4*)(af + (long)(t0 + i) * DD + c + 4);
    }
    __syncthreads();
    const int j = tid;
    float av[8] = {0.f}, aa[8] = {0.f};
    for (int k = 0; k < DD; k += 4) {
        const float4 wv = *(const float4*)(Wv2 + (long)j * DD + k);
        const float4 wa = *(const float4*)(Wa1 + (long)j * DD + k);
        #pragma unroll
        for (int i = 0; i < 8; ++i) {
            const float4 x = *(const float4*)&vs[i][k];
            av[i] += wv.x * x.x + wv.y * x.y + wv.z * x.z + wv.w * x.w;
            const float4 y = *(const float4*)&as_[i][k];
            aa[i] += wa.x * y.x + wa.y * y.y + wa.z * y.z + wa.w * y.w;
        }
    }
    float p[8];
    #pragma unroll
    for (int i = 0; i < 8; ++i)
        p[i] = fmaxf(av[i], 0.f) * fmaxf(aa[i], 0.f);
    #pragma unroll
    for (int off = 32; off > 0; off >>= 1)
        #pragma unroll
        for (int i = 0; i < 8; ++i) p[i] += __shfl_xor(p[i], off);
    const int lane = tid & 63, wv_ = tid >> 6;
    if (lane == 0)
        #pragma unroll
        for (int i = 0; i < 8; ++i) red[wv_][i] = p[i];
    __syncthreads();
    if (tid < 8) {
        float d = red[0][tid] + red[1][tid] + red[2][tid] + red[3][tid];
        d = fmaxf(d * (1.f / 16.f), 0.f);
        const float thr = thrp[0] * 10.0f / (float)TT;
        pred[t0 + tid] = (d > thr * (cs[t0 + tid] + EPSF)) ? 1.0f : 0.0f;
    }
}

// ---------------------------------------------------------------------------
// Split v_fea/a_fea fp32 -> bf16 h/l pairs. grid.y: 0=v, 1=a.
// ---------------------------------------------------------------------------
__global__ __launch_bounds__(256)
void split_feat(const float* __restrict__ vf, const float* __restrict__ af,
                u16* __restrict__ vfh, u16* __restrict__ vfl,
                u16* __restrict__ afh, u16* __restrict__ afl)
{
    const long i4 = ((long)blockIdx.x * 256 + threadIdx.x) * 4;
    const float* src = blockIdx.y ? af : vf;
    u16* dh = blockIdx.y ? afh : vfh;
    u16* dl = blockIdx.y ? afl : vfl;
    float4 a = *(const float4*)(src + i4);
    ushort4 h4, l4; u16 h;
    h = f2bf(a.x); h4.x = h; l4.x = f2bf(a.x - bf2f(h));
    h = f2bf(a.y); h4.y = h; l4.y = f2bf(a.y - bf2f(h));
    h = f2bf(a.z); h4.z = h; l4.z = f2bf(a.z - bf2f(h));
    h = f2bf(a.w); h4.w = h; l4.w = f2bf(a.w - bf2f(h));
    *(ushort4*)(dh + i4) = h4;
    *(ushort4*)(dl + i4) = l4;
}

// ---------------------------------------------------------------------------
// Split/convert 6 weight matrices into Wsp: [Wv1h Wv1l Wv2h Wv2l Wa1h Wa1l
// Wa2h Wa2l Wvfcb Wafcb], each DD*DD. grid.y = task 0..5.
// ---------------------------------------------------------------------------
__global__ __launch_bounds__(256)
void split_w(const float* __restrict__ w0, const float* __restrict__ w1,
             const float* __restrict__ w2, const float* __restrict__ w3,
             const float* __restrict__ w4, const float* __restrict__ w5,
             u16* __restrict__ out)
{
    const int t = blockIdx.y;
    const float* w = (t == 0) ? w0 : (t == 1) ? w1 : (t == 2) ? w2
                   : (t == 3) ? w3 : (t == 4) ? w4 : w5;
    const int i4 = (blockIdx.x * 256 + threadIdx.x) * 4;
    float4 a = *(const float4*)(w + i4);
    if (t < 4) {
        u16* oh = out + (size_t)t * 2 * DD * DD;
        u16* ol = oh + DD * DD;
        ushort4 h4, l4; u16 h;
        h = f2bf(a.x); h4.x = h; l4.x = f2bf(a.x - bf2f(h));
        h = f2bf(a.y); h4.y = h; l4.y = f2bf(a.y - bf2f(h));
        h = f2bf(a.z); h4.z = h; l4.z = f2bf(a.z - bf2f(h));
        h = f2bf(a.w); h4.w = h; l4.w = f2bf(a.w - bf2f(h));
        *(ushort4*)(oh + i4) = h4;
        *(ushort4*)(ol + i4) = l4;
    } else {
        u16* ob = out + (size_t)8 * DD * DD + (size_t)(t - 4) * DD * DD;
        ushort4 o;
        o.x = f2bf(a.x); o.y = f2bf(a.y); o.z = f2bf(a.z); o.w = f2bf(a.w);
        *(ushort4*)(ob + i4) = o;
    }
}

// ---------------------------------------------------------------------------
// LayerNorm both branches + fuse. 4 rows/block, 1 wave per row. fp32 in/out.
// ---------------------------------------------------------------------------
__global__ __launch_bounds__(256)
void ln_fuse_kernel(const float* __restrict__ yv, const float* __restrict__ ya,
                    const float* __restrict__ g, const float* __restrict__ b,
                    float* __restrict__ fuse, float* __restrict__ vpsp,
                    float* __restrict__ apsp)
{
    const long row = (long)blockIdx.x * 4 + (threadIdx.x >> 6);
    const int lane = threadIdx.x & 63;
    const float4 xv = *(const float4*)(yv + row * DD + lane * 4);
    const float4 xa = *(const float4*)(ya + row * DD + lane * 4);
    float sv = xv.x + xv.y + xv.z + xv.w;
    float sa = xa.x + xa.y + xa.z + xa.w;
    #pragma unroll
    for (int off = 32; off > 0; off >>= 1) {
        sv += __shfl_xor(sv, off);
        sa += __shfl_xor(sa, off);
    }
    const float mv = sv * (1.f / 256.f);
    const float ma = sa * (1.f / 256.f);
    const float dv0 = xv.x - mv, dv1 = xv.y - mv, dv2 = xv.z - mv, dv3 = xv.w - mv;
    const float da0 = xa.x - ma, da1 = xa.y - ma, da2 = xa.z - ma, da3 = xa.w - ma;
    float qv = dv0 * dv0 + dv1 * dv1 + dv2 * dv2 + dv3 * dv3;
    float qa = da0 * da0 + da1 * da1 + da2 * da2 + da3 * da3;
    #pragma unroll
    for (int off = 32; off > 0; off >>= 1) {
        qv += __shfl_xor(qv, off);
        qa += __shfl_xor(qa, off);
    }
    const float rv = rsqrtf(qv * (1.f / 256.f) + 1e-6f);
    const float ra = rsqrtf(qa * (1.f / 256.f) + 1e-6f);
    const float4 gg = *(const float4*)(g + lane * 4);
    const float4 bb = *(const float4*)(b + lane * 4);
    float4 ov, oa, of;
    ov.x = dv0 * rv * gg.x + bb.x; ov.y = dv1 * rv * gg.y + bb.y;
    ov.z = dv2 * rv * gg.z + bb.z; ov.w = dv3 * rv * gg.w + bb.w;
    oa.x = da0 * ra * gg.x + bb.x; oa.y = da1 * ra * gg.y + bb.y;
    oa.z = da2 * ra * gg.z + bb.z; oa.w = da3 * ra * gg.w + bb.w;
    of.x = 0.5f * (ov.x + oa.x); of.y = 0.5f * (ov.y + oa.y);
    of.z = 0.5f * (ov.z + oa.z); of.w = 0.5f * (ov.w + oa.w);
    *(float4*)(vpsp + row * DD + lane * 4) = ov;
    *(float4*)(apsp + row * DD + lane * 4) = oa;
    *(float4*)(fuse + row * DD + lane * 4) = of;
}

extern "C" void kernel_launch(void* const* d_in, const int* in_sizes, int n_in,
                              void* d_out, int out_size, void* d_ws, size_t ws_size,
                              hipStream_t stream)
{
    const float* a_fea = (const float*)d_in[0];
    const float* v_fea = (const float*)d_in[1];
    const float* thrp  = (const float*)d_in[2];
    const float* Wv1   = (const float*)d_in[3];
    const float* Wv2   = (const float*)d_in[4];
    const float* Wvfc  = (const float*)d_in[5];
    const float* Wa1   = (const float*)d_in[6];
    const float* Wa2   = (const float*)d_in[7];
    const float* Wafc  = (const float*)d_in[8];
    const float* lng   = (const float*)d_in[9];
    const float* lnb   = (const float*)d_in[10];

    const long MT = (long)NBATCH * TT;
    float* out_fuse = (float*)d_out;
    float* out_vpsp = out_fuse + MT * DD;
    float* out_apsp = out_vpsp + MT * DD;
    float* out_pred = out_apsp + MT * DD;

    // ws: v2h v2l a1h a1l yvin yain v1T a2T (8xfb) | rs cs | Wsp(10xDDDD) |
    //     beta(67MB) betaT(67MB). vfh/vfl/afh/afl (transient) alias beta's
    //     front (dead before score writes beta). yv/ya fp32 alias slots 0-3.
    char* ws = (char*)d_ws;
    const size_t fb = (size_t)MT * DD * sizeof(u16);
    const size_t sumB = (size_t)MT * sizeof(float);
    u16* v2h  = (u16*)(ws + 0 * fb);
    u16* v2l  = (u16*)(ws + 1 * fb);
    u16* a1h  = (u16*)(ws + 2 * fb);
    u16* a1l  = (u16*)(ws + 3 * fb);
    u16* yvin = (u16*)(ws + 4 * fb);
    u16* yain = (u16*)(ws + 5 * fb);
    u16* v1T  = (u16*)(ws + 6 * fb);
    u16* a2T  = (u16*)(ws + 7 * fb);
    char* p = ws + 8 * fb;
    float* rs = (float*)(p + 0 * sumB);
    float* cs = (float*)(p + 1 * sumB);
    u16* Wsp  = (u16*)(p + 2 * sumB);
    char* q = p + 2 * sumB + 10 * DD * DD * sizeof(u16);
    const size_t betaB = (size_t)NBATCH * TT * TT * sizeof(u16);   // 67 MB
    u16* beta  = (u16*)q;
    u16* betaT = (u16*)(q + betaB);
    u16* vfh = (u16*)q;            // transient splits, dead before score
    u16* vfl = vfh + MT * DD;
    u16* afh = vfl + MT * DD;
    u16* afl = afh + MT * DD;
    float* yv = (float*)(ws + 0 * fb);
    float* ya = (float*)(ws + 2 * fb);

    hipMemsetAsync(rs, 0, 2 * sumB, stream);

    const dim3 blk(256, 1, 1);

    split_feat<<<dim3((unsigned)(MT * DD / 1024), 2, 1), blk, 0, stream>>>(
        v_fea, a_fea, vfh, vfl, afh, afl);
    split_w<<<dim3(DD * DD / 1024, 6, 1), blk, 0, stream>>>(
        Wv1, Wv2, Wa1, Wa2, Wvfc, Wafc, Wsp);

    proj_kernel<<<dim3(DD / 64, (unsigned)(MT / 64), 4), blk, 0, stream>>>(
        vfh, vfl, afh, afl, Wsp, v2h, v2l, a1h, a1l, v1T, a2T);

    score_kernel<<<dim3(TT / 128, TT / 128, NBATCH), blk, 0, stream>>>(
        v2h, v2l, a1h, a1l, beta, betaT, rs, cs);
    pred_exact<<<dim3(TT / 8, 1, 1), blk, 0, stream>>>(
        v_fea, a_fea, Wv2, Wa1, cs, thrp, out_pred);

    pv_kernel<<<dim3(DD / 64, TT / 128, 2 * NBATCH), blk, 0, stream>>>(
        beta, betaT, a2T, v1T, rs, cs, thrp, v_fea, a_fea, yvin, yain);

    fc_kernel<<<dim3(DD / 64, (unsigned)(MT / 128), 2), blk, 0, stream>>>(
        yvin, Wsp + 8 * DD * DD, yv);
    ln_fuse_kernel<<<dim3((unsigned)(MT / 4), 1, 1), blk, 0, stream>>>(
        yv, ya, lng, lnb, out_fuse, out_vpsp, out_apsp);
}

// Round 6
// 445.096 us; speedup vs baseline: 2.4853x; 1.0028x over previous
//
#include <hip/hip_runtime.h>
#include <math.h>

#define TT 2048
#define DD 256
#define NBATCH 8
#define EPSF 1e-8f

typedef unsigned short u16;
typedef __attribute__((ext_vector_type(8))) short short8;
typedef __attribute__((ext_vector_type(4))) float f32x4;

__device__ __forceinline__ u16 f2bf(float x) {
    unsigned int u = __builtin_bit_cast(unsigned int, x);
    u += 0x7fffu + ((u >> 16) & 1u);
    return (u16)(u >> 16);
}
__device__ __forceinline__ float bf2f(u16 h) {
    return __builtin_bit_cast(float, (unsigned int)h << 16);
}

// MFMA-fragment LDS index for a [rows x 32k] bf16 tile:
// elem(row,k) -> (((row>>4)*4+(k>>3))*16+(row&15))*8+(k&7)
// Fragment read for 16-row subtile t is ds_read_b128 at (t*64+lane)*8.
__device__ __forceinline__ int frag_dst(int row, int k) {
    return (((row >> 4) * 4 + (k >> 3)) * 16 + (row & 15)) * 8 + (k & 7);
}

template<int BR>
__device__ __forceinline__ void stage_tile(const u16* __restrict__ g, u16* s,
                                           int row0, int k0, int ldk, int tid)
{
    #pragma unroll
    for (int i = 0; i < BR / 64; ++i) {
        const int c = tid + 256 * i;
        const int row = c >> 2, q = c & 3;
        *(int4*)(s + frag_dst(row, q * 8)) =
            *(const int4*)(g + (long)(row0 + row) * ldk + k0 + q * 8);
    }
}

// ---------------------------------------------------------------------------
// Combined projections. z = 0:v2(split h/l) 1:a1(split h/l)
//                        2:v1 -> v1T (register-transposed bf16)
//                        3:a2 -> a2T
// 3-term split-bf16 MFMA (rel err ~3e-6). BM=BN=64, 2x2 waves.
// ---------------------------------------------------------------------------
__global__ __launch_bounds__(256)
void proj_kernel(const u16* __restrict__ vfh, const u16* __restrict__ vfl,
                 const u16* __restrict__ afh, const u16* __restrict__ afl,
                 const u16* __restrict__ Wsp,
                 u16* __restrict__ v2h, u16* __restrict__ v2l,
                 u16* __restrict__ a1h, u16* __restrict__ a1l,
                 u16* __restrict__ v1T, u16* __restrict__ a2T)
{
    const int zz = blockIdx.z;
    const u16* Ah = (zz == 1 || zz == 3) ? afh : vfh;
    const u16* Al = (zz == 1 || zz == 3) ? afl : vfl;
    const int widx = (zz == 0) ? 2 : (zz == 1) ? 4 : (zz == 2) ? 0 : 6;
    const u16* Bh = Wsp + widx * DD * DD;
    const u16* Bl = Bh + DD * DD;
    const bool split = zz < 2;
    u16* Oh = (zz == 0) ? v2h : a1h;
    u16* Ol = (zz == 0) ? v2l : a1l;
    u16* OT = (zz == 2) ? v1T : a2T;

    __shared__ __align__(16) u16 Ah_s[64 * 32], Al_s[64 * 32];
    __shared__ __align__(16) u16 Bh_s[64 * 32], Bl_s[64 * 32];
    const int m0 = blockIdx.y * 64, n0 = blockIdx.x * 64;
    const int tid = threadIdx.x, lane = tid & 63, w = tid >> 6;
    const int wy = w >> 1, wx = w & 1;
    f32x4 acc[2][2] = {};

    for (int k0 = 0; k0 < DD; k0 += 32) {
        stage_tile<64>(Ah, Ah_s, m0, k0, DD, tid);
        stage_tile<64>(Al, Al_s, m0, k0, DD, tid);
        stage_tile<64>(Bh, Bh_s, n0, k0, DD, tid);
        stage_tile<64>(Bl, Bl_s, n0, k0, DD, tid);
        __syncthreads();
        short8 ah[2], al[2], bh[2], bl[2];
        #pragma unroll
        for (int i = 0; i < 2; ++i) {
            ah[i] = *(const short8*)(Ah_s + ((wy * 2 + i) * 64 + lane) * 8);
            al[i] = *(const short8*)(Al_s + ((wy * 2 + i) * 64 + lane) * 8);
        }
        #pragma unroll
        for (int j = 0; j < 2; ++j) {
            bh[j] = *(const short8*)(Bh_s + ((wx * 2 + j) * 64 + lane) * 8);
            bl[j] = *(const short8*)(Bl_s + ((wx * 2 + j) * 64 + lane) * 8);
        }
        #pragma unroll
        for (int i = 0; i < 2; ++i)
            #pragma unroll
            for (int j = 0; j < 2; ++j) {
                acc[i][j] = __builtin_amdgcn_mfma_f32_16x16x32_bf16(ah[i], bl[j], acc[i][j], 0, 0, 0);
                acc[i][j] = __builtin_amdgcn_mfma_f32_16x16x32_bf16(al[i], bh[j], acc[i][j], 0, 0, 0);
                acc[i][j] = __builtin_amdgcn_mfma_f32_16x16x32_bf16(ah[i], bh[j], acc[i][j], 0, 0, 0);
            }
        __syncthreads();
    }
    const int quad = lane >> 4, col = lane & 15;
    #pragma unroll
    for (int i = 0; i < 2; ++i)
        #pragma unroll
        for (int j = 0; j < 2; ++j) {
            const int c = n0 + (wx * 2 + j) * 16 + col;
            const int rbase = m0 + (wy * 2 + i) * 16 + quad * 4;
            if (split) {
                #pragma unroll
                for (int r = 0; r < 4; ++r) {
                    const float v = fmaxf(acc[i][j][r], 0.f);
                    const u16 h = f2bf(v);
                    Oh[(long)(rbase + r) * DD + c] = h;
                    Ol[(long)(rbase + r) * DD + c] = f2bf(v - bf2f(h));
                }
            } else {
                // transposed: OT[b][d=c][t]; 4 consecutive t = one b64 store
                short4 pk;
                pk.x = (short)f2bf(fmaxf(acc[i][j][0], 0.f));
                pk.y = (short)f2bf(fmaxf(acc[i][j][1], 0.f));
                pk.z = (short)f2bf(fmaxf(acc[i][j][2], 0.f));
                pk.w = (short)f2bf(fmaxf(acc[i][j][3], 0.f));
                const int b = rbase >> 11, t = rbase & (TT - 1);
                *(short4*)(OT + ((long)b * DD + c) * TT + t) = pk;
            }
        }
}

// ---------------------------------------------------------------------------
// Scores: beta(bf16) = relu(v2.a1/16), 3-term split MFMA.
// Emits beta (row-major, coalesced), betaT via LDS-transpose epilogue
// (coalesced int4 stores), and fp32-exact rs/cs atomics. BM=BN=128.
// ---------------------------------------------------------------------------
__global__ __launch_bounds__(256)
void score_kernel(const u16* __restrict__ v2h, const u16* __restrict__ v2l,
                  const u16* __restrict__ a1h, const u16* __restrict__ a1l,
                  u16* __restrict__ beta, u16* __restrict__ betaT,
                  float* __restrict__ rs, float* __restrict__ cs)
{
    // S also serves as the 128x128 transpose buffer (stride 136, 34 KB)
    __shared__ __align__(16) u16 S[128 * 136];
    u16* Ah_s = S;
    u16* Al_s = S + 4096;
    u16* Bh_s = S + 8192;
    u16* Bl_s = S + 12288;
    const int z = blockIdx.z;
    const int m0 = blockIdx.y * 128, n0 = blockIdx.x * 128;
    const int tid = threadIdx.x, lane = tid & 63, w = tid >> 6;
    const int wy = w >> 1, wx = w & 1;
    const long zoff = (long)z * TT * DD;
    f32x4 acc[4][4] = {};

    for (int k0 = 0; k0 < DD; k0 += 32) {
        stage_tile<128>(v2h + zoff, Ah_s, m0, k0, DD, tid);
        stage_tile<128>(v2l + zoff, Al_s, m0, k0, DD, tid);
        stage_tile<128>(a1h + zoff, Bh_s, n0, k0, DD, tid);
        stage_tile<128>(a1l + zoff, Bl_s, n0, k0, DD, tid);
        __syncthreads();
        short8 ah[4], al[4], bh[4], bl[4];
        #pragma unroll
        for (int i = 0; i < 4; ++i) {
            ah[i] = *(const short8*)(Ah_s + ((wy * 4 + i) * 64 + lane) * 8);
            al[i] = *(const short8*)(Al_s + ((wy * 4 + i) * 64 + lane) * 8);
        }
        #pragma unroll
        for (int j = 0; j < 4; ++j) {
            bh[j] = *(const short8*)(Bh_s + ((wx * 4 + j) * 64 + lane) * 8);
            bl[j] = *(const short8*)(Bl_s + ((wx * 4 + j) * 64 + lane) * 8);
        }
        #pragma unroll
        for (int i = 0; i < 4; ++i)
            #pragma unroll
            for (int j = 0; j < 4; ++j) {
                acc[i][j] = __builtin_amdgcn_mfma_f32_16x16x32_bf16(ah[i], bl[j], acc[i][j], 0, 0, 0);
                acc[i][j] = __builtin_amdgcn_mfma_f32_16x16x32_bf16(al[i], bh[j], acc[i][j], 0, 0, 0);
                acc[i][j] = __builtin_amdgcn_mfma_f32_16x16x32_bf16(ah[i], bh[j], acc[i][j], 0, 0, 0);
            }
        __syncthreads();
    }

    const int quad = lane >> 4, col = lane & 15;
    const float scale = 1.f / 16.f;
    // beta (row-major, coalesced) + keep scaled values in acc
    #pragma unroll
    for (int i = 0; i < 4; ++i)
        #pragma unroll
        for (int j = 0; j < 4; ++j) {
            const int c = n0 + (wx * 4 + j) * 16 + col;
            const int rbase = m0 + (wy * 4 + i) * 16 + quad * 4;
            #pragma unroll
            for (int r = 0; r < 4; ++r) {
                float v = fmaxf(acc[i][j][r] * scale, 0.f);
                acc[i][j][r] = v;
                beta[((long)z * TT + rbase + r) * TT + c] = f2bf(v);
            }
        }
    // row sums (fp32-exact)
    #pragma unroll
    for (int i = 0; i < 4; ++i)
        #pragma unroll
        for (int r = 0; r < 4; ++r) {
            float rp = 0.f;
            #pragma unroll
            for (int j = 0; j < 4; ++j) rp += acc[i][j][r];
            rp += __shfl_xor(rp, 1); rp += __shfl_xor(rp, 2);
            rp += __shfl_xor(rp, 4); rp += __shfl_xor(rp, 8);
            if (col == 0) {
                const int row = m0 + (wy * 4 + i) * 16 + quad * 4 + r;
                atomicAdd(&rs[(long)z * TT + row], rp);
            }
        }
    // col sums
    #pragma unroll
    for (int j = 0; j < 4; ++j) {
        float cp = 0.f;
        #pragma unroll
        for (int i = 0; i < 4; ++i)
            #pragma unroll
            for (int r = 0; r < 4; ++r) cp += acc[i][j][r];
        cp += __shfl_xor(cp, 16); cp += __shfl_xor(cp, 32);
        if (lane < 16) {
            const int c = n0 + (wx * 4 + j) * 16 + col;
            atomicAdd(&cs[(long)z * TT + c], cp);
        }
    }
    // betaT via LDS transpose: S[cl][rl] (stride 136), then coalesced stores
    __syncthreads();
    #pragma unroll
    for (int i = 0; i < 4; ++i)
        #pragma unroll
        for (int j = 0; j < 4; ++j) {
            const int cl = (wx * 4 + j) * 16 + col;
            const int rl = (wy * 4 + i) * 16 + quad * 4;
            short4 pk;
            pk.x = (short)f2bf(acc[i][j][0]);
            pk.y = (short)f2bf(acc[i][j][1]);
            pk.z = (short)f2bf(acc[i][j][2]);
            pk.w = (short)f2bf(acc[i][j][3]);
            *(short4*)(S + cl * 136 + rl) = pk;
        }
    __syncthreads();
    #pragma unroll
    for (int it = 0; it < 8; ++it) {
        const int idx = tid + 256 * it;
        const int cl = idx >> 4, tq = idx & 15;
        const int4 v = *(const int4*)(S + cl * 136 + tq * 8);
        *(int4*)(betaT + ((long)z * TT + n0 + cl) * TT + m0 + tq * 8) = v;
    }
}

// ---------------------------------------------------------------------------
// Unified PV, full-D tile. zz<8: v-attends-a (P=beta, sums=rs, V=a2T,
// resid=v_fea); zz>=8: a-attends-v (P=betaT, sums=cs, V=v1T, resid=a_fea).
// BM=128, BN=256(=D), K=TT. 512 threads = 8 waves (2x4). Each beta row is
// staged+thresholded exactly ONCE; thresholded row sums accumulate in-loop.
// Register prefetch of k+1 hides global latency across the MFMA phase.
// grid=(zz,m0) with zz fastest: all m-blocks of a batch share an XCD -> VT
// slice is L2-resident.
// ---------------------------------------------------------------------------
__global__ __launch_bounds__(512)
void pv_kernel(const u16* __restrict__ beta, const u16* __restrict__ betaT,
               const u16* __restrict__ a2T, const u16* __restrict__ v1T,
               const float* __restrict__ rs, const float* __restrict__ cs,
               const float* __restrict__ thrp,
               const float* __restrict__ v_fea, const float* __restrict__ a_fea,
               u16* __restrict__ yvin, u16* __restrict__ yain)
{
    __shared__ __align__(16) u16 A_s[128 * 32], B_s[256 * 32];
    __shared__ float sthr[128], sA[128], ssum[128];
    const int zz = blockIdx.x;
    const int m0 = blockIdx.y * 128;
    const int z = zz & 7;
    const bool av = zz >= 8;
    const u16* P      = av ? betaT : beta;
    const u16* VT     = av ? v1T : a2T;
    const float* sums = av ? cs : rs;
    const float* resid = av ? a_fea : v_fea;
    u16* outb         = av ? yain : yvin;

    const int tid = threadIdx.x, lane = tid & 63, w = tid >> 6;
    const int wy = w >> 2, wx = w & 3;
    const float thr = thrp[0] * 10.0f / (float)TT;
    if (tid < 128) {
        const float s = sums[(long)z * TT + m0 + tid];
        sA[tid] = s; sthr[tid] = thr * (s + EPSF); ssum[tid] = 0.f;
    }
    __syncthreads();
    f32x4 acc[4][4] = {};
    float rpart = 0.f;
    const int arow = tid >> 2, aq = tid & 3;          // A: 128 rows x 4 chunks
    const u16* Pp = P + ((long)z * TT + m0 + arow) * TT + aq * 8;
    const u16* V0 = VT + (long)z * DD * TT + (long)arow * TT + aq * 8;
    const u16* V1 = V0 + (long)128 * TT;

    int4 Ar  = *(const int4*)(Pp);
    int4 Br0 = *(const int4*)(V0);
    int4 Br1 = *(const int4*)(V1);

    for (int k0 = 0; k0 < TT; k0 += 32) {
        // consume prefetched regs: threshold A, copy B
        union { int4 v; u16 us[8]; } U;
        U.v = Ar;
        const float ct = sthr[arow];
        float ss = 0.f;
        #pragma unroll
        for (int t = 0; t < 8; ++t) {
            const float v = bf2f(U.us[t]);
            if (v > ct) ss += v; else U.us[t] = 0;
        }
        rpart += ss;
        *(int4*)(A_s + frag_dst(arow, aq * 8)) = U.v;
        *(int4*)(B_s + frag_dst(arow, aq * 8)) = Br0;
        *(int4*)(B_s + frag_dst(arow + 128, aq * 8)) = Br1;
        __syncthreads();
        // prefetch k0+32 (last iter: harmless re-load of same address)
        const int kn = (k0 + 32 < TT) ? (k0 + 32) : k0;
        Ar  = *(const int4*)(Pp + kn);
        Br0 = *(const int4*)(V0 + kn);
        Br1 = *(const int4*)(V1 + kn);
        // fragments + MFMA
        short8 a[4], b[4];
        #pragma unroll
        for (int i = 0; i < 4; ++i)
            a[i] = *(const short8*)(A_s + ((wy * 4 + i) * 64 + lane) * 8);
        #pragma unroll
        for (int j = 0; j < 4; ++j)
            b[j] = *(const short8*)(B_s + ((wx * 4 + j) * 64 + lane) * 8);
        #pragma unroll
        for (int i = 0; i < 4; ++i)
            #pragma unroll
            for (int j = 0; j < 4; ++j)
                acc[i][j] = __builtin_amdgcn_mfma_f32_16x16x32_bf16(a[i], b[j], acc[i][j], 0, 0, 0);
        __syncthreads();
    }
    atomicAdd(&ssum[arow], rpart);
    __syncthreads();

    const int quad = lane >> 4, col = lane & 15;
    #pragma unroll
    for (int i = 0; i < 4; ++i)
        #pragma unroll
        for (int j = 0; j < 4; ++j) {
            const int c = (wx * 4 + j) * 16 + col;
            #pragma unroll
            for (int r = 0; r < 4; ++r) {
                const int lrow = (wy * 4 + i) * 16 + quad * 4 + r;
                const int row = m0 + lrow;
                const float inv = 1.0f / (ssum[lrow] + EPSF * (sA[lrow] + EPSF));
                const float v = acc[i][j][r] * inv + resid[((long)z * TT + row) * DD + c];
                outb[((long)z * TT + row) * DD + c] = f2bf(v);
            }
        }
}

// ---------------------------------------------------------------------------
// FC: y = relu(yin @ Wfc^T) fp32 out. z selects branch via fixed strides.
// ---------------------------------------------------------------------------
__global__ __launch_bounds__(256)
void fc_kernel(const u16* __restrict__ Ain, const u16* __restrict__ Wb,
               float* __restrict__ Cf)
{
    const int z = blockIdx.z;
    const u16* A = Ain + (size_t)z * (size_t)NBATCH * TT * DD;
    const u16* B = Wb + (size_t)z * DD * DD;
    float* C = Cf + (size_t)z * (size_t)NBATCH * TT * DD;
    __shared__ __align__(16) u16 A_s[128 * 32], B_s[64 * 32];
    const int m0 = blockIdx.y * 128, n0 = blockIdx.x * 64;
    const int tid = threadIdx.x, lane = tid & 63, w = tid >> 6;
    const int wy = w >> 1, wx = w & 1;
    f32x4 acc[4][2] = {};
    for (int k0 = 0; k0 < DD; k0 += 32) {
        stage_tile<128>(A, A_s, m0, k0, DD, tid);
        stage_tile<64>(B, B_s, n0, k0, DD, tid);
        __syncthreads();
        short8 a[4], b[2];
        #pragma unroll
        for (int i = 0; i < 4; ++i)
            a[i] = *(const short8*)(A_s + ((wy * 4 + i) * 64 + lane) * 8);
        #pragma unroll
        for (int j = 0; j < 2; ++j)
            b[j] = *(const short8*)(B_s + ((wx * 2 + j) * 64 + lane) * 8);
        #pragma unroll
        for (int i = 0; i < 4; ++i)
            #pragma unroll
            for (int j = 0; j < 2; ++j)
                acc[i][j] = __builtin_amdgcn_mfma_f32_16x16x32_bf16(a[i], b[j], acc[i][j], 0, 0, 0);
        __syncthreads();
    }
    const int quad = lane >> 4, col = lane & 15;
    #pragma unroll
    for (int i = 0; i < 4; ++i)
        #pragma unroll
        for (int j = 0; j < 2; ++j) {
            const int c = n0 + (wx * 2 + j) * 16 + col;
            #pragma unroll
            for (int r = 0; r < 4; ++r) {
                const int row = m0 + (wy * 4 + i) * 16 + quad * 4 + r;
                C[(long)row * DD + c] = fmaxf(acc[i][j][r], 0.f);
            }
        }
}

// ---------------------------------------------------------------------------
// Exact fp32 pred: recompute v2[0,t], a1[0,t] and their dot; compare.
// ---------------------------------------------------------------------------
__global__ __launch_bounds__(256)
void pred_exact(const float* __restrict__ vf, const float* __restrict__ af,
                const float* __restrict__ Wv2, const float* __restrict__ Wa1,
                const float* __restrict__ cs, const float* __restrict__ thrp,
                float* __restrict__ pred)
{
    __shared__ float vs[8][260];
    __shared__ float as_[8][260];
    __shared__ float red[4][8];
    const int t0 = blockIdx.x * 8;
    const int tid = threadIdx.x;
    {
        const int i = tid >> 5, c = (tid & 31) * 8;
        *(float4*)&vs[i][c] = *(const float4*)(vf + (long)(t0 + i) * DD + c);
        *(float4*)&vs[i][c + 4] = *(const float4*)(vf + (long)(t0 + i) * DD + c + 4);
        *(float4*)&as_[i][c] = *(const float4*)(af + (long)(t0 + i) * DD + c);
        *(float4*)&as_[i][c + 4] = *(const float4*)(af + (long)(t0 + i) * DD + c + 4);
    }
    __syncthreads();
    const int j = tid;
    float av[8] = {0.f}, aa[8] = {0.f};
    for (int k = 0; k < DD; k += 4) {
        const float4 wv = *(const float4*)(Wv2 + (long)j * DD + k);
        const float4 wa = *(const float4*)(Wa1 + (long)j * DD + k);
        #pragma unroll
        for (int i = 0; i < 8; ++i) {
            const float4 x = *(const float4*)&vs[i][k];
            av[i] += wv.x * x.x + wv.y * x.y + wv.z * x.z + wv.w * x.w;
            const float4 y = *(const float4*)&as_[i][k];
            aa[i] += wa.x * y.x + wa.y * y.y + wa.z * y.z + wa.w * y.w;
        }
    }
    float p[8];
    #pragma unroll
    for (int i = 0; i < 8; ++i)
        p[i] = fmaxf(av[i], 0.f) * fmaxf(aa[i], 0.f);
    #pragma unroll
    for (int off = 32; off > 0; off >>= 1)
        #pragma unroll
        for (int i = 0; i < 8; ++i) p[i] += __shfl_xor(p[i], off);
    const int lane = tid & 63, wv_ = tid >> 6;
    if (lane == 0)
        #pragma unroll
        for (int i = 0; i < 8; ++i) red[wv_][i] = p[i];
    __syncthreads();
    if (tid < 8) {
        float d = red[0][tid] + red[1][tid] + red[2][tid] + red[3][tid];
        d = fmaxf(d * (1.f / 16.f), 0.f);
        const float thr = thrp[0] * 10.0f / (float)TT;
        pred[t0 + tid] = (d > thr * (cs[t0 + tid] + EPSF)) ? 1.0f : 0.0f;
    }
}

// ---------------------------------------------------------------------------
// Split v_fea/a_fea fp32 -> bf16 h/l pairs. grid.y: 0=v, 1=a.
// ---------------------------------------------------------------------------
__global__ __launch_bounds__(256)
void split_feat(const float* __restrict__ vf, const float* __restrict__ af,
                u16* __restrict__ vfh, u16* __restrict__ vfl,
                u16* __restrict__ afh, u16* __restrict__ afl)
{
    const long i4 = ((long)blockIdx.x * 256 + threadIdx.x) * 4;
    const float* src = blockIdx.y ? af : vf;
    u16* dh = blockIdx.y ? afh : vfh;
    u16* dl = blockIdx.y ? afl : vfl;
    float4 a = *(const float4*)(src + i4);
    ushort4 h4, l4; u16 h;
    h = f2bf(a.x); h4.x = h; l4.x = f2bf(a.x - bf2f(h));
    h = f2bf(a.y); h4.y = h; l4.y = f2bf(a.y - bf2f(h));
    h = f2bf(a.z); h4.z = h; l4.z = f2bf(a.z - bf2f(h));
    h = f2bf(a.w); h4.w = h; l4.w = f2bf(a.w - bf2f(h));
    *(ushort4*)(dh + i4) = h4;
    *(ushort4*)(dl + i4) = l4;
}

// ---------------------------------------------------------------------------
// Split/convert 6 weight matrices into Wsp: [Wv1h Wv1l Wv2h Wv2l Wa1h Wa1l
// Wa2h Wa2l Wvfcb Wafcb], each DD*DD. grid.y = task 0..5.
// ---------------------------------------------------------------------------
__global__ __launch_bounds__(256)
void split_w(const float* __restrict__ w0, const float* __restrict__ w1,
             const float* __restrict__ w2, const float* __restrict__ w3,
             const float* __restrict__ w4, const float* __restrict__ w5,
             u16* __restrict__ out)
{
    const int t = blockIdx.y;
    const float* w = (t == 0) ? w0 : (t == 1) ? w1 : (t == 2) ? w2
                   : (t == 3) ? w3 : (t == 4) ? w4 : w5;
    const int i4 = (blockIdx.x * 256 + threadIdx.x) * 4;
    float4 a = *(const float4*)(w + i4);
    if (t < 4) {
        u16* oh = out + (size_t)t * 2 * DD * DD;
        u16* ol = oh + DD * DD;
        ushort4 h4, l4; u16 h;
        h = f2bf(a.x); h4.x = h; l4.x = f2bf(a.x - bf2f(h));
        h = f2bf(a.y); h4.y = h; l4.y = f2bf(a.y - bf2f(h));
        h = f2bf(a.z); h4.z = h; l4.z = f2bf(a.z - bf2f(h));
        h = f2bf(a.w); h4.w = h; l4.w = f2bf(a.w - bf2f(h));
        *(ushort4*)(oh + i4) = h4;
        *(ushort4*)(ol + i4) = l4;
    } else {
        u16* ob = out + (size_t)8 * DD * DD + (size_t)(t - 4) * DD * DD;
        ushort4 o;
        o.x = f2bf(a.x); o.y = f2bf(a.y); o.z = f2bf(a.z); o.w = f2bf(a.w);
        *(ushort4*)(ob + i4) = o;
    }
}

// ---------------------------------------------------------------------------
// LayerNorm both branches + fuse. 4 rows/block, 1 wave per row. fp32 in/out.
// ---------------------------------------------------------------------------
__global__ __launch_bounds__(256)
void ln_fuse_kernel(const float* __restrict__ yv, const float* __restrict__ ya,
                    const float* __restrict__ g, const float* __restrict__ b,
                    float* __restrict__ fuse, float* __restrict__ vpsp,
                    float* __restrict__ apsp)
{
    const long row = (long)blockIdx.x * 4 + (threadIdx.x >> 6);
    const int lane = threadIdx.x & 63;
    const float4 xv = *(const float4*)(yv + row * DD + lane * 4);
    const float4 xa = *(const float4*)(ya + row * DD + lane * 4);
    float sv = xv.x + xv.y + xv.z + xv.w;
    float sa = xa.x + xa.y + xa.z + xa.w;
    #pragma unroll
    for (int off = 32; off > 0; off >>= 1) {
        sv += __shfl_xor(sv, off);
        sa += __shfl_xor(sa, off);
    }
    const float mv = sv * (1.f / 256.f);
    const float ma = sa * (1.f / 256.f);
    const float dv0 = xv.x - mv, dv1 = xv.y - mv, dv2 = xv.z - mv, dv3 = xv.w - mv;
    const float da0 = xa.x - ma, da1 = xa.y - ma, da2 = xa.z - ma, da3 = xa.w - ma;
    float qv = dv0 * dv0 + dv1 * dv1 + dv2 * dv2 + dv3 * dv3;
    float qa = da0 * da0 + da1 * da1 + da2 * da2 + da3 * da3;
    #pragma unroll
    for (int off = 32; off > 0; off >>= 1) {
        qv += __shfl_xor(qv, off);
        qa += __shfl_xor(qa, off);
    }
    const float rv = rsqrtf(qv * (1.f / 256.f) + 1e-6f);
    const float ra = rsqrtf(qa * (1.f / 256.f) + 1e-6f);
    const float4 gg = *(const float4*)(g + lane * 4);
    const float4 bb = *(const float4*)(b + lane * 4);
    float4 ov, oa, of;
    ov.x = dv0 * rv * gg.x + bb.x; ov.y = dv1 * rv * gg.y + bb.y;
    ov.z = dv2 * rv * gg.z + bb.z; ov.w = dv3 * rv * gg.w + bb.w;
    oa.x = da0 * ra * gg.x + bb.x; oa.y = da1 * ra * gg.y + bb.y;
    oa.z = da2 * ra * gg.z + bb.z; oa.w = da3 * ra * gg.w + bb.w;
    of.x = 0.5f * (ov.x + oa.x); of.y = 0.5f * (ov.y + oa.y);
    of.z = 0.5f * (ov.z + oa.z); of.w = 0.5f * (ov.w + oa.w);
    *(float4*)(vpsp + row * DD + lane * 4) = ov;
    *(float4*)(apsp + row * DD + lane * 4) = oa;
    *(float4*)(fuse + row * DD + lane * 4) = of;
}

extern "C" void kernel_launch(void* const* d_in, const int* in_sizes, int n_in,
                              void* d_out, int out_size, void* d_ws, size_t ws_size,
                              hipStream_t stream)
{
    const float* a_fea = (const float*)d_in[0];
    const float* v_fea = (const float*)d_in[1];
    const float* thrp  = (const float*)d_in[2];
    const float* Wv1   = (const float*)d_in[3];
    const float* Wv2   = (const float*)d_in[4];
    const float* Wvfc  = (const float*)d_in[5];
    const float* Wa1   = (const float*)d_in[6];
    const float* Wa2   = (const float*)d_in[7];
    const float* Wafc  = (const float*)d_in[8];
    const float* lng   = (const float*)d_in[9];
    const float* lnb   = (const float*)d_in[10];

    const long MT = (long)NBATCH * TT;
    float* out_fuse = (float*)d_out;
    float* out_vpsp = out_fuse + MT * DD;
    float* out_apsp = out_vpsp + MT * DD;
    float* out_pred = out_apsp + MT * DD;

    // ws: v2h v2l a1h a1l yvin yain v1T a2T (8xfb) | rs cs | Wsp(10xDDDD) |
    //     beta(67MB) betaT(67MB). vfh/vfl/afh/afl (transient) alias beta's
    //     front (dead before score writes beta). yv/ya fp32 alias slots 0-3.
    char* ws = (char*)d_ws;
    const size_t fb = (size_t)MT * DD * sizeof(u16);
    const size_t sumB = (size_t)MT * sizeof(float);
    u16* v2h  = (u16*)(ws + 0 * fb);
    u16* v2l  = (u16*)(ws + 1 * fb);
    u16* a1h  = (u16*)(ws + 2 * fb);
    u16* a1l  = (u16*)(ws + 3 * fb);
    u16* yvin = (u16*)(ws + 4 * fb);
    u16* yain = (u16*)(ws + 5 * fb);
    u16* v1T  = (u16*)(ws + 6 * fb);
    u16* a2T  = (u16*)(ws + 7 * fb);
    char* p = ws + 8 * fb;
    float* rs = (float*)(p + 0 * sumB);
    float* cs = (float*)(p + 1 * sumB);
    u16* Wsp  = (u16*)(p + 2 * sumB);
    char* q = p + 2 * sumB + 10 * DD * DD * sizeof(u16);
    const size_t betaB = (size_t)NBATCH * TT * TT * sizeof(u16);   // 67 MB
    u16* beta  = (u16*)q;
    u16* betaT = (u16*)(q + betaB);
    u16* vfh = (u16*)q;            // transient splits, dead before score
    u16* vfl = vfh + MT * DD;
    u16* afh = vfl + MT * DD;
    u16* afl = afh + MT * DD;
    float* yv = (float*)(ws + 0 * fb);
    float* ya = (float*)(ws + 2 * fb);

    hipMemsetAsync(rs, 0, 2 * sumB, stream);

    const dim3 blk(256, 1, 1);

    split_feat<<<dim3((unsigned)(MT * DD / 1024), 2, 1), blk, 0, stream>>>(
        v_fea, a_fea, vfh, vfl, afh, afl);
    split_w<<<dim3(DD * DD / 1024, 6, 1), blk, 0, stream>>>(
        Wv1, Wv2, Wa1, Wa2, Wvfc, Wafc, Wsp);

    proj_kernel<<<dim3(DD / 64, (unsigned)(MT / 64), 4), blk, 0, stream>>>(
        vfh, vfl, afh, afl, Wsp, v2h, v2l, a1h, a1l, v1T, a2T);

    score_kernel<<<dim3(TT / 128, TT / 128, NBATCH), blk, 0, stream>>>(
        v2h, v2l, a1h, a1l, beta, betaT, rs, cs);
    pred_exact<<<dim3(TT / 8, 1, 1), blk, 0, stream>>>(
        v_fea, a_fea, Wv2, Wa1, cs, thrp, out_pred);

    // grid: x = zz (batch+dir, XCD-affine), y = m0 tile; 512 threads
    pv_kernel<<<dim3(2 * NBATCH, TT / 128, 1), dim3(512, 1, 1), 0, stream>>>(
        beta, betaT, a2T, v1T, rs, cs, thrp, v_fea, a_fea, yvin, yain);

    fc_kernel<<<dim3(DD / 64, (unsigned)(MT / 128), 2), blk, 0, stream>>>(
        yvin, Wsp + 8 * DD * DD, yv);
    ln_fuse_kernel<<<dim3((unsigned)(MT / 4), 1, 1), blk, 0, stream>>>(
        yv, ya, lng, lnb, out_fuse, out_vpsp, out_apsp);
}